// Round 7
// baseline (240.034 us; speedup 1.0000x reference)
//
#include <hip/hip_runtime.h>

typedef unsigned short u16;
typedef unsigned int u32;
typedef unsigned long long u64;
typedef __attribute__((ext_vector_type(8))) short short8;
typedef __attribute__((ext_vector_type(4))) float f32x4;

#define MLOGC (-14426.95f)   /* -10000 * log2(e) */

// ---------- helpers ----------
__device__ __forceinline__ u16 f2bf(float f) {
  u32 u = __builtin_bit_cast(u32, f);
  u += 0x7fffu + ((u >> 16) & 1u);   // RNE
  return (u16)(u >> 16);
}

__device__ __forceinline__ float fexp2(float x) {
#if __has_builtin(__builtin_amdgcn_exp2f)
  return __builtin_amdgcn_exp2f(x);   // v_exp_f32
#else
  return exp2f(x);
#endif
}

// async global->LDS, 16B per lane. LDS dest is wave-uniform base + lane*16.
__device__ __forceinline__ void glds16(u16* lds, const u16* g) {
  __builtin_amdgcn_global_load_lds(
      (const __attribute__((address_space(1))) u32*)g,
      (__attribute__((address_space(3))) u32*)lds, 16, 0, 0);
}

#define MFMA(a, b, c) __builtin_amdgcn_mfma_f32_16x16x32_bf16((a), (b), (c), 0, 0, 0)

// LDS tile layout (XOR-swizzled), tile = [64 rows][64 u16 cols] = 8 KiB:
//   physical 16B-chunk slot p of row r holds logical col-chunk (p ^ (r&7)).
// b128 reads hit 8 distinct 16B regions per half-wave (4-way = b128 minimum).
//
// P/V k-permutation: PV contracts over k, so P and V share π(k)=(k&15)*4+(k>>4)
// within each 64-key group. P: lane's j=0..3 values land contiguously -> one
// ds_write_b64. V: π baked into vtc storage at the gemm_fused V epilogue.

// ---------- kernel 1: fused prep (x cvt | W transposes | mask scan) ----------
// grid 9220: [0,8192) cvt x; [8192,8960) W_qkv transpose tiles (48x16);
// [8960,9216) W_proj tiles (16x16); [9216,9220) per-batch mask scan.
__global__ __launch_bounds__(256) void prep(const float* __restrict__ x,
                                            const int* __restrict__ mask,
                                            const float* __restrict__ Wqkv,
                                            const float* __restrict__ Wproj,
                                            u16* __restrict__ xb,
                                            u16* __restrict__ wqkvt,
                                            u16* __restrict__ wprojt,
                                            int* __restrict__ s2t,
                                            int* __restrict__ nkbuf) {
  __shared__ float tile[64][65];
  __shared__ int wtot[4];
  __shared__ int wbase[5];
  const int bid = blockIdx.x, t = threadIdx.x;

  if (bid < 8192) {                    // ---- role: x fp32 -> bf16 ----
    int i = bid * 256 + t;
    float4 v = ((const float4*)x)[i];
    union { u16 s[4]; u64 ll; } u;
    u.s[0] = f2bf(v.x); u.s[1] = f2bf(v.y); u.s[2] = f2bf(v.z); u.s[3] = f2bf(v.w);
    ((u64*)xb)[i] = u.ll;
    return;
  }
  if (bid < 9216) {                    // ---- role: W transpose+cvt ----
    const float* Wm; u16* Wt; int Cc, bj, bi;
    if (bid < 8960) { int tt = bid - 8192; Wm = Wqkv;  Wt = wqkvt;  Cc = 3072; bj = tt % 48; bi = tt / 48; }
    else            { int tt = bid - 8960; Wm = Wproj; Wt = wprojt; Cc = 1024; bj = tt & 15; bi = tt >> 4; }
    const int r = t >> 4, c4 = (t & 15) << 2;
    for (int rr = r; rr < 64; rr += 16) {
      float4 v = *(const float4*)&Wm[(size_t)(bi * 64 + rr) * Cc + bj * 64 + c4];
      tile[rr][c4] = v.x; tile[rr][c4 + 1] = v.y; tile[rr][c4 + 2] = v.z; tile[rr][c4 + 3] = v.w;
    }
    __syncthreads();
    for (int rr = r; rr < 64; rr += 16) {
      union { u16 s[4]; u64 ll; } u;
      u.s[0] = f2bf(tile[c4][rr]);
      u.s[1] = f2bf(tile[c4 + 1][rr]);
      u.s[2] = f2bf(tile[c4 + 2][rr]);
      u.s[3] = f2bf(tile[c4 + 3][rr]);
      *(u64*)&Wt[(size_t)(bj * 64 + rr) * 1024 + bi * 64 + c4] = u.ll;
    }
    return;
  }
  // ---- role: per-batch stable partition of key tokens ----
  const int b = bid - 9216;
  const int lane = t & 63, w = t >> 6;
  int m8[8], c = 0;
  #pragma unroll
  for (int j = 0; j < 8; j++) {
    m8[j] = (mask[b * 2048 + t * 8 + j] == 1);
    c += m8[j];
  }
  int incl = c;
  #pragma unroll
  for (int off = 1; off < 64; off <<= 1) {
    int v = __shfl_up(incl, off);
    if (lane >= off) incl += v;
  }
  if (lane == 63) wtot[w] = incl;
  __syncthreads();
  if (t == 0) {
    int s = 0;
    for (int i = 0; i < 4; i++) { wbase[i] = s; s += wtot[i]; }
    wbase[4] = s;
  }
  __syncthreads();
  const int nk = wbase[4];
  int urun = wbase[w] + incl - c;
  #pragma unroll
  for (int j = 0; j < 8; j++) {
    int tok = t * 8 + j;
    int slot = m8[j] ? urun : nk + (tok - urun);
    s2t[b * 2048 + slot] = b * 2048 + tok;
    urun += m8[j];
  }
  if (t == 0) nkbuf[b] = nk;
}

// ---------- kernel 2: fused Q/K/V GEMM, flattened grid, compacted K/V ----------
// 1536 blocks: [0,512) Q, [512,1024) K, [1024,1536) V^T. K/V blocks whose whole
// 128-slot range is masked-out exit immediately (uniform); scheduler backfills.
//  Q: qbuf[token][1024]      = x · Wq        (A=x rows direct, B=wqkvt rows n)
//  K: kc[b][slot][1024]      = x[s2t] · Wk   (A rows gathered by slot->token)
//  V: vtc[b][d][π-slot]      = Wv^T · x[s2t] (B rows gathered; π within 64-grp)
__global__ __launch_bounds__(256, 4) void gemm_fused(const u16* __restrict__ xb,
                                                     const u16* __restrict__ wqkvt,
                                                     const int* __restrict__ s2t,
                                                     const int* __restrict__ nkbuf,
                                                     u16* __restrict__ qbuf,
                                                     u16* __restrict__ kc,
                                                     u16* __restrict__ vtc) {
  __shared__ u16 Asm[128 * 64];
  __shared__ u16 Bsm[128 * 64];
  const int bid = blockIdx.x;
  const int role = bid >> 9;            // 0=Q 1=K 2=V
  const int sub = bid & 511;
  const int tid = threadIdx.x, lane = tid & 63, w = tid >> 6;
  const int quad = lane >> 4, l15 = lane & 15;
  const int wm = (w >> 1) * 64, wn = (w & 1) * 64;
  const int srow = lane >> 3;
  const int gcc = ((lane & 7) ^ srow) * 8;
  const int rx8 = (l15 & 7);

  int m0, n0;
  const u16 *Asrc, *Bsrc;
  if (role == 2) { m0 = (sub & 7) * 128; n0 = (sub >> 3) * 128; }
  else           { m0 = (sub >> 3) * 128; n0 = (sub & 7) * 128; }
  if (role == 1 && (m0 & 2047) >= nkbuf[m0 >> 11]) return;
  if (role == 2 && (n0 & 2047) >= nkbuf[n0 >> 11]) return;

  // per-lane source row ids for the 4 staged chunks
  int arow[4], brow[4];
  #pragma unroll
  for (int c = 0; c < 4; ++c) {
    int rit = (w * 4 + c) * 8 + srow;   // row within the 128-tile
    if (role == 0)      { arow[c] = m0 + rit;            brow[c] = n0 + rit; }
    else if (role == 1) { arow[c] = s2t[m0 + rit];       brow[c] = 1024 + n0 + rit; }
    else                { arow[c] = 2048 + m0 + rit;     brow[c] = s2t[n0 + rit]; }
  }
  Asrc = (role == 2) ? wqkvt : xb;
  Bsrc = (role == 2) ? xb : wqkvt;

  f32x4 acc[4][4];
  #pragma unroll
  for (int i = 0; i < 4; i++)
    #pragma unroll
    for (int j = 0; j < 4; j++)
      #pragma unroll
      for (int r = 0; r < 4; r++) acc[i][j][r] = 0.f;

  for (int kt = 0; kt < 1024; kt += 64) {
    __syncthreads();
    #pragma unroll
    for (int c = 0; c < 4; ++c) {
      int chunk = w * 4 + c;
      glds16(&Asm[chunk * 512], &Asrc[(size_t)arow[c] * 1024 + kt + gcc]);
      glds16(&Bsm[chunk * 512], &Bsrc[(size_t)brow[c] * 1024 + kt + gcc]);
    }
    __syncthreads();
    #pragma unroll
    for (int ks = 0; ks < 2; ++ks) {
      int pc = ((ks * 4 + quad) ^ rx8) * 8;
      short8 av[4], bv[4];
      #pragma unroll
      for (int i = 0; i < 4; i++)
        av[i] = *(const short8*)&Asm[(wm + i * 16 + l15) * 64 + pc];
      #pragma unroll
      for (int j = 0; j < 4; j++)
        bv[j] = *(const short8*)&Bsm[(wn + j * 16 + l15) * 64 + pc];
      #pragma unroll
      for (int i = 0; i < 4; i++)
        #pragma unroll
        for (int j = 0; j < 4; j++)
          acc[i][j] = MFMA(av[i], bv[j], acc[i][j]);
    }
  }

  if (role == 2) {
    #pragma unroll
    for (int j = 0; j < 4; j++) {
      int col = n0 + wn + j * 16 + l15;           // global slot 0..8191
      int bb = col >> 11, sl = col & 2047;
      // π within the 64-slot group: sl2 = g*64 + (sl&15)*4 + ((sl>>4)&3)
      int sl2 = (sl & ~63) | ((sl & 15) << 2) | ((sl >> 4) & 3);
      #pragma unroll
      for (int i = 0; i < 4; i++)
        #pragma unroll
        for (int r = 0; r < 4; r++) {
          int row = m0 + wm + i * 16 + quad * 4 + r;   // d in 0..1023
          vtc[(size_t)(bb * 1024 + row) * 2048 + sl2] = f2bf(acc[i][j][r]);
        }
    }
  } else {
    u16* dst = (role == 0) ? qbuf : kc;   // rows are tokens (Q) or slots (K); both dense
    #pragma unroll
    for (int i = 0; i < 4; i++)
      #pragma unroll
      for (int j = 0; j < 4; j++) {
        int col = n0 + wn + j * 16 + l15;
        #pragma unroll
        for (int r = 0; r < 4; r++) {
          int row = m0 + wm + i * 16 + quad * 4 + r;
          dst[(size_t)row * 1024 + col] = f2bf(acc[i][j][r]);
        }
      }
  }
}

// ---------- kernel 3: flash attention over compacted keys ----------
// grid (16 h, 4 b, 16 qt) — qt varies slowest (stride 64 in dispatch order ->
// K/V-sharing blocks land on the SAME XCD for L2 reuse). 256 thr = 4 waves;
// wave owns 32 q-rows. Mask = register compare slot<nk. 4 blocks/CU.
__global__ __launch_bounds__(256, 4) void attn_kernel(const u16* __restrict__ q,
                                                      const u16* __restrict__ kc,
                                                      const u16* __restrict__ vtc,
                                                      const int* __restrict__ nkbuf,
                                                      u16* __restrict__ ao) {
  __shared__ u16 Ksm[64 * 64];          // swizzled [k_local][d]
  __shared__ u16 Vsm[64 * 64];          // swizzled [d][π(k_local)]
  __shared__ u16 Psm[4 * 32 * 72];      // per-wave [32 q][π(k)], stride 72
  const int h = blockIdx.x, b = blockIdx.y, qt = blockIdx.z;
  const int tid = threadIdx.x, lane = tid & 63, w = tid >> 6;
  const int quad = lane >> 4, l15 = lane & 15;
  const int q0 = qt * 128 + w * 32;     // wave's q base within batch
  const int srow = lane >> 3;
  const int gcc = ((lane & 7) ^ srow) * 8;
  const int rx8 = (l15 & 7);
  const float C1 = 0.18033688f;         // 0.125 * log2(e)
  const int nk = nkbuf[b];
  const int ntiles = (nk + 63) >> 6;

  // Q fragments (A-operand): row=lane&15, k=quad*8+j, straight from global
  short8 qf[2][2];
  #pragma unroll
  for (int i = 0; i < 2; i++)
    #pragma unroll
    for (int ks = 0; ks < 2; ks++)
      qf[i][ks] = *(const short8*)&q[(size_t)(b * 2048 + q0 + i * 16 + l15) * 1024 +
                                     h * 64 + ks * 32 + quad * 8];

  f32x4 o[2][4];
  float lsum[2][4];
  #pragma unroll
  for (int i = 0; i < 2; i++)
    #pragma unroll
    for (int r = 0; r < 4; r++) {
      lsum[i][r] = 0.f;
      #pragma unroll
      for (int jd = 0; jd < 4; jd++) o[i][jd][r] = 0.f;
    }

  for (int t = 0; t < ntiles; ++t) {
    const int k0 = t * 64;
    __syncthreads();
    #pragma unroll
    for (int c = 0; c < 2; ++c) {
      int chunk = w * 2 + c;
      int r = chunk * 8 + srow;
      glds16(&Ksm[chunk * 512], &kc[(size_t)(b * 2048 + k0 + r) * 1024 + h * 64 + gcc]);
      glds16(&Vsm[chunk * 512], &vtc[(size_t)(b * 1024 + h * 64 + r) * 2048 + k0 + gcc]);
    }
    __syncthreads();

    // S = Q K^T
    f32x4 s[2][4];
    #pragma unroll
    for (int i = 0; i < 2; i++)
      #pragma unroll
      for (int j = 0; j < 4; j++)
        #pragma unroll
        for (int r = 0; r < 4; r++) s[i][j][r] = 0.f;
    #pragma unroll
    for (int ks = 0; ks < 2; ks++) {
      int pc = ((ks * 4 + quad) ^ rx8) * 8;
      short8 kf[4];
      #pragma unroll
      for (int j = 0; j < 4; j++)
        kf[j] = *(const short8*)&Ksm[(j * 16 + l15) * 64 + pc];
      #pragma unroll
      for (int i = 0; i < 2; i++)
        #pragma unroll
        for (int j = 0; j < 4; j++) s[i][j] = MFMA(qf[i][ks], kf[j], s[i][j]);
    }

    // additive mask: slot < nk unmasked (0), else -inf — pure register compare
    float mlog[4];
    #pragma unroll
    for (int j = 0; j < 4; j++)
      mlog[j] = (k0 + j * 16 + l15 < nk) ? 0.f : MLOGC;

    // p = exp2(s*C1 + mlog); per-lane partial row sums; store P bf16 at π(k):
    // lane's four j-values are contiguous -> 2x v_perm pack + one ds_write_b64.
    #pragma unroll
    for (int i = 0; i < 2; i++) {
      #pragma unroll
      for (int r = 0; r < 4; r++) {
        int prow = i * 16 + quad * 4 + r;
        u32 pv[4];
        float ps = 0.f;
        #pragma unroll
        for (int j = 0; j < 4; j++) {
          float p = fexp2(__builtin_fmaf(s[i][j][r], C1, mlog[j]));
          ps += p;
          pv[j] = __builtin_bit_cast(u32, p) + 0x8000u;   // round-half-up
        }
        lsum[i][r] += ps;
        u32 lo = __builtin_amdgcn_perm(pv[1], pv[0], 0x07060302u);
        u32 hi = __builtin_amdgcn_perm(pv[3], pv[2], 0x07060302u);
        *(u64*)&Psm[w * 2304 + prow * 72 + l15 * 4] = (u64)lo | ((u64)hi << 32);
      }
    }

    // O += P V  (both operands in π(k)-space; per-wave-private P: no barrier)
    #pragma unroll
    for (int ks = 0; ks < 2; ks++) {
      int pcv = ((ks * 4 + quad) ^ rx8) * 8;   // Vsm swizzled
      int kk = ks * 32 + quad * 8;             // Psm not swizzled
      short8 pf[2], vf[4];
      #pragma unroll
      for (int i = 0; i < 2; i++)
        pf[i] = *(const short8*)&Psm[w * 2304 + (i * 16 + l15) * 72 + kk];
      #pragma unroll
      for (int jd = 0; jd < 4; jd++)
        vf[jd] = *(const short8*)&Vsm[(jd * 16 + l15) * 64 + pcv];
      #pragma unroll
      for (int i = 0; i < 2; i++)
        #pragma unroll
        for (int jd = 0; jd < 4; jd++) o[i][jd] = MFMA(pf[i], vf[jd], o[i][jd]);
    }
  }

  // epilogue: reduce row sums across the 16 lanes sharing each row, normalize, store
  #pragma unroll
  for (int i = 0; i < 2; i++)
    #pragma unroll
    for (int r = 0; r < 4; r++) {
      float l = lsum[i][r];
      #pragma unroll
      for (int off = 8; off >= 1; off >>= 1) l += __shfl_xor(l, off);
      float inv = 1.f / l;
      size_t row = (size_t)(b * 2048 + q0 + i * 16 + quad * 4 + r);
      #pragma unroll
      for (int jd = 0; jd < 4; jd++)
        ao[row * 1024 + h * 64 + jd * 16 + l15] = f2bf(o[i][jd][r] * inv);
    }
}

// ---------- kernel 4: output projection + bias ----------
__global__ __launch_bounds__(256, 3) void gemm_proj(const u16* __restrict__ A,
                                                    const u16* __restrict__ Bt,
                                                    const float* __restrict__ bias,
                                                    float* __restrict__ out) {
  __shared__ u16 Asm[128 * 64];
  __shared__ u16 Bsm[128 * 64];
  const int tid = threadIdx.x, lane = tid & 63, w = tid >> 6;
  const int quad = lane >> 4, l15 = lane & 15;
  const int m0 = blockIdx.y * 128, n0 = blockIdx.x * 128;
  const int wm = (w >> 1) * 64, wn = (w & 1) * 64;
  const int srow = lane >> 3;
  const int gcc = ((lane & 7) ^ srow) * 8;
  const int rx8 = (l15 & 7);
  f32x4 acc[4][4];
  #pragma unroll
  for (int i = 0; i < 4; i++)
    #pragma unroll
    for (int j = 0; j < 4; j++)
      #pragma unroll
      for (int r = 0; r < 4; r++) acc[i][j][r] = 0.f;

  for (int kt = 0; kt < 1024; kt += 64) {
    __syncthreads();
    #pragma unroll
    for (int c = 0; c < 4; ++c) {
      int chunk = w * 4 + c;
      int row = chunk * 8 + srow;
      glds16(&Asm[chunk * 512], &A[(size_t)(m0 + row) * 1024 + kt + gcc]);
      glds16(&Bsm[chunk * 512], &Bt[(size_t)(n0 + row) * 1024 + kt + gcc]);
    }
    __syncthreads();
    #pragma unroll
    for (int ks = 0; ks < 2; ++ks) {
      int pc = ((ks * 4 + quad) ^ rx8) * 8;
      short8 av[4], bv[4];
      #pragma unroll
      for (int i = 0; i < 4; i++)
        av[i] = *(const short8*)&Asm[(wm + i * 16 + l15) * 64 + pc];
      #pragma unroll
      for (int j = 0; j < 4; j++)
        bv[j] = *(const short8*)&Bsm[(wn + j * 16 + l15) * 64 + pc];
      #pragma unroll
      for (int i = 0; i < 4; i++)
        #pragma unroll
        for (int j = 0; j < 4; j++)
          acc[i][j] = MFMA(av[i], bv[j], acc[i][j]);
    }
  }

  #pragma unroll
  for (int j = 0; j < 4; j++) {
    int col = n0 + wn + j * 16 + l15;
    float bj = bias[col];
    #pragma unroll
    for (int i = 0; i < 4; i++) {
      #pragma unroll
      for (int r = 0; r < 4; r++) {
        int row = m0 + wm + i * 16 + quad * 4 + r;
        out[(size_t)row * 1024 + col] = acc[i][j][r] + bj;
      }
    }
  }
}

// ---------- launch ----------
extern "C" void kernel_launch(void* const* d_in, const int* in_sizes, int n_in,
                              void* d_out, int out_size, void* d_ws, size_t ws_size,
                              hipStream_t stream) {
  (void)in_sizes; (void)n_in; (void)out_size; (void)ws_size;
  const float* x     = (const float*)d_in[0];
  const int*   mask  = (const int*)d_in[1];
  const float* Wqkv  = (const float*)d_in[2];
  const float* Wproj = (const float*)d_in[3];
  const float* bproj = (const float*)d_in[4];
  float* out = (float*)d_out;
  char* ws = (char*)d_ws;

  size_t off = 0;
  u16* xb     = (u16*)(ws + off); off += 8192ull * 1024 * 2;   // x bf16 [8192][1024]
  u16* wqkvt  = (u16*)(ws + off); off += 3072ull * 1024 * 2;   // Wqkv^T bf16 [3072][1024]
  u16* wprojt = (u16*)(ws + off); off += 1024ull * 1024 * 2;   // Wproj^T bf16 [1024][1024]
  u16* qbuf   = (u16*)(ws + off); off += 8192ull * 1024 * 2;   // Q bf16 [8192][1024]
  u16* kcbuf  = (u16*)(ws + off); off += 4096ull * 2048 * 2;   // K compact [b][slot][1024]
  u16* vtcbuf = (u16*)(ws + off); off += 4096ull * 2048 * 2;   // V^T compact [b][d][π-slot]
  u16* aobuf  = (u16*)(ws + off); off += 8192ull * 1024 * 2;   // attn out bf16 [8192][1024]
  int* s2t    = (int*)(ws + off); off += 8192ull * 4;          // slot -> global token
  int* nkbuf  = (int*)(ws + off); off += 4 * 4;                // per-batch nk

  prep<<<9220, 256, 0, stream>>>(x, mask, Wqkv, Wproj, xb, wqkvt, wprojt, s2t, nkbuf);
  gemm_fused<<<1536, 256, 0, stream>>>(xb, wqkvt, s2t, nkbuf, qbuf, kcbuf, vtcbuf);
  attn_kernel<<<dim3(16, 4, 16), 256, 0, stream>>>(qbuf, kcbuf, vtcbuf, nkbuf, aobuf);
  gemm_proj<<<dim3(8, 64), 256, 0, stream>>>(aobuf, wprojt, bproj, out);
}

// Round 8
// 231.984 us; speedup vs baseline: 1.0347x; 1.0347x over previous
//
#include <hip/hip_runtime.h>

typedef unsigned short u16;
typedef unsigned int u32;
typedef unsigned long long u64;
typedef __attribute__((ext_vector_type(8))) short short8;
typedef __attribute__((ext_vector_type(4))) float f32x4;

#define MLOGC (-14426.95f)   /* -10000 * log2(e) */

// ---------- helpers ----------
__device__ __forceinline__ u16 f2bf(float f) {
  u32 u = __builtin_bit_cast(u32, f);
  u += 0x7fffu + ((u >> 16) & 1u);   // RNE
  return (u16)(u >> 16);
}

__device__ __forceinline__ float fexp2(float x) {
#if __has_builtin(__builtin_amdgcn_exp2f)
  return __builtin_amdgcn_exp2f(x);   // v_exp_f32
#else
  return exp2f(x);
#endif
}

// async global->LDS, 16B per lane. LDS dest is wave-uniform base + lane*16.
__device__ __forceinline__ void glds16(u16* lds, const u16* g) {
  __builtin_amdgcn_global_load_lds(
      (const __attribute__((address_space(1))) u32*)g,
      (__attribute__((address_space(3))) u32*)lds, 16, 0, 0);
}

#define MFMA(a, b, c) __builtin_amdgcn_mfma_f32_16x16x32_bf16((a), (b), (c), 0, 0, 0)

// LDS tile layout (XOR-swizzled), tile = [64 rows][64 u16 cols] = 8 KiB:
//   physical 16B-chunk slot p of row r holds logical col-chunk (p ^ (r&7)).
// b128 reads hit 8 distinct 16B regions per half-wave (4-way = b128 minimum).

// ---------- kernel 1: fused prep (x cvt | W transposes | mask scan) ----------
// grid 9220: [0,8192) cvt x; [8192,8960) W_qkv transpose tiles (48x16);
// [8960,9216) W_proj tiles (16x16); [9216,9220) per-batch mask scan.
__global__ __launch_bounds__(256) void prep(const float* __restrict__ x,
                                            const int* __restrict__ mask,
                                            const float* __restrict__ Wqkv,
                                            const float* __restrict__ Wproj,
                                            u16* __restrict__ xb,
                                            u16* __restrict__ wqkvt,
                                            u16* __restrict__ wprojt,
                                            int* __restrict__ s2t,
                                            int* __restrict__ nkbuf) {
  __shared__ float tile[64][65];
  __shared__ int wtot[4];
  __shared__ int wbase[5];
  const int bid = blockIdx.x, t = threadIdx.x;

  if (bid < 8192) {                    // ---- role: x fp32 -> bf16 ----
    int i = bid * 256 + t;
    float4 v = ((const float4*)x)[i];
    union { u16 s[4]; u64 ll; } u;
    u.s[0] = f2bf(v.x); u.s[1] = f2bf(v.y); u.s[2] = f2bf(v.z); u.s[3] = f2bf(v.w);
    ((u64*)xb)[i] = u.ll;
    return;
  }
  if (bid < 9216) {                    // ---- role: W transpose+cvt ----
    const float* Wm; u16* Wt; int Cc, bj, bi;
    if (bid < 8960) { int tt = bid - 8192; Wm = Wqkv;  Wt = wqkvt;  Cc = 3072; bj = tt % 48; bi = tt / 48; }
    else            { int tt = bid - 8960; Wm = Wproj; Wt = wprojt; Cc = 1024; bj = tt & 15; bi = tt >> 4; }
    const int r = t >> 4, c4 = (t & 15) << 2;
    for (int rr = r; rr < 64; rr += 16) {
      float4 v = *(const float4*)&Wm[(size_t)(bi * 64 + rr) * Cc + bj * 64 + c4];
      tile[rr][c4] = v.x; tile[rr][c4 + 1] = v.y; tile[rr][c4 + 2] = v.z; tile[rr][c4 + 3] = v.w;
    }
    __syncthreads();
    for (int rr = r; rr < 64; rr += 16) {
      union { u16 s[4]; u64 ll; } u;
      u.s[0] = f2bf(tile[c4][rr]);
      u.s[1] = f2bf(tile[c4 + 1][rr]);
      u.s[2] = f2bf(tile[c4 + 2][rr]);
      u.s[3] = f2bf(tile[c4 + 3][rr]);
      *(u64*)&Wt[(size_t)(bj * 64 + rr) * 1024 + bi * 64 + c4] = u.ll;
    }
    return;
  }
  // ---- role: per-batch stable partition of key tokens ----
  const int b = bid - 9216;
  const int lane = t & 63, w = t >> 6;
  int m8[8], c = 0;
  #pragma unroll
  for (int j = 0; j < 8; j++) {
    m8[j] = (mask[b * 2048 + t * 8 + j] == 1);
    c += m8[j];
  }
  int incl = c;
  #pragma unroll
  for (int off = 1; off < 64; off <<= 1) {
    int v = __shfl_up(incl, off);
    if (lane >= off) incl += v;
  }
  if (lane == 63) wtot[w] = incl;
  __syncthreads();
  if (t == 0) {
    int s = 0;
    for (int i = 0; i < 4; i++) { wbase[i] = s; s += wtot[i]; }
    wbase[4] = s;
  }
  __syncthreads();
  const int nk = wbase[4];
  int urun = wbase[w] + incl - c;
  #pragma unroll
  for (int j = 0; j < 8; j++) {
    int tok = t * 8 + j;
    int slot = m8[j] ? urun : nk + (tok - urun);
    s2t[b * 2048 + slot] = b * 2048 + tok;
    urun += m8[j];
  }
  if (t == 0) nkbuf[b] = nk;
}

// ---------- kernel 2: fused Q/K/V GEMM, flattened grid, compacted K/V ----------
// 1536 blocks: [0,512) Q, [512,1024) K, [1024,1536) V^T. K/V blocks whose whole
// 128-slot range is masked-out exit immediately (uniform); scheduler backfills.
//  Q: qbuf[token][1024]      = x · Wq        (A=x rows direct, B=wqkvt rows n)
//  K: kc[b][slot][1024]      = x[s2t] · Wk   (A rows gathered by slot->token)
//  V: vtc[b][d][slot]        = Wv^T · x[s2t] (B rows gathered; contiguous store)
__global__ __launch_bounds__(256, 4) void gemm_fused(const u16* __restrict__ xb,
                                                     const u16* __restrict__ wqkvt,
                                                     const int* __restrict__ s2t,
                                                     const int* __restrict__ nkbuf,
                                                     u16* __restrict__ qbuf,
                                                     u16* __restrict__ kc,
                                                     u16* __restrict__ vtc) {
  __shared__ u16 Asm[128 * 64];
  __shared__ u16 Bsm[128 * 64];
  const int bid = blockIdx.x;
  const int role = bid >> 9;            // 0=Q 1=K 2=V
  const int sub = bid & 511;
  const int tid = threadIdx.x, lane = tid & 63, w = tid >> 6;
  const int quad = lane >> 4, l15 = lane & 15;
  const int wm = (w >> 1) * 64, wn = (w & 1) * 64;
  const int srow = lane >> 3;
  const int gcc = ((lane & 7) ^ srow) * 8;
  const int rx8 = (l15 & 7);

  int m0, n0;
  const u16 *Asrc, *Bsrc;
  if (role == 2) { m0 = (sub & 7) * 128; n0 = (sub >> 3) * 128; }
  else           { m0 = (sub >> 3) * 128; n0 = (sub & 7) * 128; }
  if (role == 1 && (m0 & 2047) >= nkbuf[m0 >> 11]) return;
  if (role == 2 && (n0 & 2047) >= nkbuf[n0 >> 11]) return;

  // per-lane source row ids for the 4 staged chunks
  int arow[4], brow[4];
  #pragma unroll
  for (int c = 0; c < 4; ++c) {
    int rit = (w * 4 + c) * 8 + srow;   // row within the 128-tile
    if (role == 0)      { arow[c] = m0 + rit;            brow[c] = n0 + rit; }
    else if (role == 1) { arow[c] = s2t[m0 + rit];       brow[c] = 1024 + n0 + rit; }
    else                { arow[c] = 2048 + m0 + rit;     brow[c] = s2t[n0 + rit]; }
  }
  Asrc = (role == 2) ? wqkvt : xb;
  Bsrc = (role == 2) ? xb : wqkvt;

  f32x4 acc[4][4];
  #pragma unroll
  for (int i = 0; i < 4; i++)
    #pragma unroll
    for (int j = 0; j < 4; j++)
      #pragma unroll
      for (int r = 0; r < 4; r++) acc[i][j][r] = 0.f;

  for (int kt = 0; kt < 1024; kt += 64) {
    __syncthreads();
    #pragma unroll
    for (int c = 0; c < 4; ++c) {
      int chunk = w * 4 + c;
      glds16(&Asm[chunk * 512], &Asrc[(size_t)arow[c] * 1024 + kt + gcc]);
      glds16(&Bsm[chunk * 512], &Bsrc[(size_t)brow[c] * 1024 + kt + gcc]);
    }
    __syncthreads();
    #pragma unroll
    for (int ks = 0; ks < 2; ++ks) {
      int pc = ((ks * 4 + quad) ^ rx8) * 8;
      short8 av[4], bv[4];
      #pragma unroll
      for (int i = 0; i < 4; i++)
        av[i] = *(const short8*)&Asm[(wm + i * 16 + l15) * 64 + pc];
      #pragma unroll
      for (int j = 0; j < 4; j++)
        bv[j] = *(const short8*)&Bsm[(wn + j * 16 + l15) * 64 + pc];
      #pragma unroll
      for (int i = 0; i < 4; i++)
        #pragma unroll
        for (int j = 0; j < 4; j++)
          acc[i][j] = MFMA(av[i], bv[j], acc[i][j]);
    }
  }

  if (role == 2) {
    #pragma unroll
    for (int j = 0; j < 4; j++) {
      int col = n0 + wn + j * 16 + l15;           // global slot 0..8191
      int bb = col >> 11, sl = col & 2047;
      #pragma unroll
      for (int i = 0; i < 4; i++)
        #pragma unroll
        for (int r = 0; r < 4; r++) {
          int row = m0 + wm + i * 16 + quad * 4 + r;   // d in 0..1023
          vtc[(size_t)(bb * 1024 + row) * 2048 + sl] = f2bf(acc[i][j][r]);
        }
    }
  } else {
    u16* dst = (role == 0) ? qbuf : kc;   // rows are tokens (Q) or slots (K); both dense
    #pragma unroll
    for (int i = 0; i < 4; i++)
      #pragma unroll
      for (int j = 0; j < 4; j++) {
        int col = n0 + wn + j * 16 + l15;
        #pragma unroll
        for (int r = 0; r < 4; r++) {
          int row = m0 + wm + i * 16 + quad * 4 + r;
          dst[(size_t)row * 1024 + col] = f2bf(acc[i][j][r]);
        }
      }
  }
}

// ---------- kernel 3: flash attention over compacted keys, fat q-tiles ----------
// grid (16 h, 4 b, 8 qt) — qt stride 64 ≡ 0 mod 8 => K/V-sharing blocks on one
// XCD. 256 thr = 4 waves; wave owns 64 q-rows (i=0..3) to amortize the per-tile
// K/V LDS reads (each wave reads the full 8KB K + 8KB V tile regardless of q).
// Mask = register compare slot<nk. VGPR-heavy: 2 blocks/CU (LDS-bound anyway).
__global__ __launch_bounds__(256, 2) void attn_kernel(const u16* __restrict__ q,
                                                      const u16* __restrict__ kc,
                                                      const u16* __restrict__ vtc,
                                                      const int* __restrict__ nkbuf,
                                                      u16* __restrict__ ao) {
  __shared__ u16 Ksm[64 * 64];          // swizzled [k_local][d]
  __shared__ u16 Vsm[64 * 64];          // swizzled [d][k_local]
  __shared__ u16 Psm[4 * 64 * 72];      // per-wave [64 q][64 k], stride 72
  const int h = blockIdx.x, b = blockIdx.y, qt = blockIdx.z;
  const int tid = threadIdx.x, lane = tid & 63, w = tid >> 6;
  const int quad = lane >> 4, l15 = lane & 15;
  const int q0 = qt * 256 + w * 64;     // wave's q base within batch
  const int srow = lane >> 3;
  const int gcc = ((lane & 7) ^ srow) * 8;
  const int rx8 = (l15 & 7);
  const float C1 = 0.18033688f;         // 0.125 * log2(e)
  const int nk = nkbuf[b];
  const int ntiles = (nk + 63) >> 6;

  // Q fragments (A-operand): row=lane&15, k=quad*8+j, straight from global
  short8 qf[4][2];
  #pragma unroll
  for (int i = 0; i < 4; i++)
    #pragma unroll
    for (int ks = 0; ks < 2; ks++)
      qf[i][ks] = *(const short8*)&q[(size_t)(b * 2048 + q0 + i * 16 + l15) * 1024 +
                                     h * 64 + ks * 32 + quad * 8];

  f32x4 o[4][4];
  float lsum[4][4];
  #pragma unroll
  for (int i = 0; i < 4; i++)
    #pragma unroll
    for (int r = 0; r < 4; r++) {
      lsum[i][r] = 0.f;
      #pragma unroll
      for (int jd = 0; jd < 4; jd++) o[i][jd][r] = 0.f;
    }

  for (int t = 0; t < ntiles; ++t) {
    const int k0 = t * 64;
    __syncthreads();
    #pragma unroll
    for (int c = 0; c < 2; ++c) {
      int chunk = w * 2 + c;
      int r = chunk * 8 + srow;
      glds16(&Ksm[chunk * 512], &kc[(size_t)(b * 2048 + k0 + r) * 1024 + h * 64 + gcc]);
      glds16(&Vsm[chunk * 512], &vtc[(size_t)(b * 1024 + h * 64 + r) * 2048 + k0 + gcc]);
    }
    __syncthreads();

    // S = Q K^T   (4 q-blocks x 4 key-blocks)
    f32x4 s[4][4];
    #pragma unroll
    for (int i = 0; i < 4; i++)
      #pragma unroll
      for (int j = 0; j < 4; j++)
        #pragma unroll
        for (int r = 0; r < 4; r++) s[i][j][r] = 0.f;
    #pragma unroll
    for (int ks = 0; ks < 2; ks++) {
      int pc = ((ks * 4 + quad) ^ rx8) * 8;
      short8 kf[4];
      #pragma unroll
      for (int j = 0; j < 4; j++)
        kf[j] = *(const short8*)&Ksm[(j * 16 + l15) * 64 + pc];
      #pragma unroll
      for (int i = 0; i < 4; i++)
        #pragma unroll
        for (int j = 0; j < 4; j++) s[i][j] = MFMA(qf[i][ks], kf[j], s[i][j]);
    }

    // additive mask: slot < nk unmasked (0), else -inf — pure register compare
    float mlog[4];
    #pragma unroll
    for (int j = 0; j < 4; j++)
      mlog[j] = (k0 + j * 16 + l15 < nk) ? 0.f : MLOGC;

    // p = exp2(s*C1 + mlog); per-lane partial row sums; store P bf16
    // (round-half-up via +0x8000 then store HIGH half -> ds_write_b16_d16_hi)
    #pragma unroll
    for (int i = 0; i < 4; i++) {
      #pragma unroll
      for (int r = 0; r < 4; r++) {
        int prow = i * 16 + quad * 4 + r;
        float ps = 0.f;
        #pragma unroll
        for (int j = 0; j < 4; j++) {
          float p = fexp2(__builtin_fmaf(s[i][j][r], C1, mlog[j]));
          ps += p;
          u32 pv = __builtin_bit_cast(u32, p) + 0x8000u;
          Psm[w * 4608 + prow * 72 + j * 16 + l15] = ((const u16*)&pv)[1];
        }
        lsum[i][r] += ps;
      }
    }

    // O += P V  (P region is per-wave private: no barrier needed)
    #pragma unroll
    for (int ks = 0; ks < 2; ks++) {
      int pcv = ((ks * 4 + quad) ^ rx8) * 8;   // Vsm swizzled
      int kk = ks * 32 + quad * 8;             // Psm not swizzled
      short8 pf[4], vf[4];
      #pragma unroll
      for (int i = 0; i < 4; i++)
        pf[i] = *(const short8*)&Psm[w * 4608 + (i * 16 + l15) * 72 + kk];
      #pragma unroll
      for (int jd = 0; jd < 4; jd++)
        vf[jd] = *(const short8*)&Vsm[(jd * 16 + l15) * 64 + pcv];
      #pragma unroll
      for (int i = 0; i < 4; i++)
        #pragma unroll
        for (int jd = 0; jd < 4; jd++) o[i][jd] = MFMA(pf[i], vf[jd], o[i][jd]);
    }
  }

  // epilogue: reduce row sums across the 16 lanes sharing each row, normalize, store
  #pragma unroll
  for (int i = 0; i < 4; i++)
    #pragma unroll
    for (int r = 0; r < 4; r++) {
      float l = lsum[i][r];
      #pragma unroll
      for (int off = 8; off >= 1; off >>= 1) l += __shfl_xor(l, off);
      float inv = 1.f / l;
      size_t row = (size_t)(b * 2048 + q0 + i * 16 + quad * 4 + r);
      #pragma unroll
      for (int jd = 0; jd < 4; jd++)
        ao[row * 1024 + h * 64 + jd * 16 + l15] = f2bf(o[i][jd][r] * inv);
    }
}

// ---------- kernel 4: output projection + bias ----------
__global__ __launch_bounds__(256, 3) void gemm_proj(const u16* __restrict__ A,
                                                    const u16* __restrict__ Bt,
                                                    const float* __restrict__ bias,
                                                    float* __restrict__ out) {
  __shared__ u16 Asm[128 * 64];
  __shared__ u16 Bsm[128 * 64];
  const int tid = threadIdx.x, lane = tid & 63, w = tid >> 6;
  const int quad = lane >> 4, l15 = lane & 15;
  const int m0 = blockIdx.y * 128, n0 = blockIdx.x * 128;
  const int wm = (w >> 1) * 64, wn = (w & 1) * 64;
  const int srow = lane >> 3;
  const int gcc = ((lane & 7) ^ srow) * 8;
  const int rx8 = (l15 & 7);
  f32x4 acc[4][4];
  #pragma unroll
  for (int i = 0; i < 4; i++)
    #pragma unroll
    for (int j = 0; j < 4; j++)
      #pragma unroll
      for (int r = 0; r < 4; r++) acc[i][j][r] = 0.f;

  for (int kt = 0; kt < 1024; kt += 64) {
    __syncthreads();
    #pragma unroll
    for (int c = 0; c < 4; ++c) {
      int chunk = w * 4 + c;
      int row = chunk * 8 + srow;
      glds16(&Asm[chunk * 512], &A[(size_t)(m0 + row) * 1024 + kt + gcc]);
      glds16(&Bsm[chunk * 512], &Bt[(size_t)(n0 + row) * 1024 + kt + gcc]);
    }
    __syncthreads();
    #pragma unroll
    for (int ks = 0; ks < 2; ++ks) {
      int pc = ((ks * 4 + quad) ^ rx8) * 8;
      short8 av[4], bv[4];
      #pragma unroll
      for (int i = 0; i < 4; i++)
        av[i] = *(const short8*)&Asm[(wm + i * 16 + l15) * 64 + pc];
      #pragma unroll
      for (int j = 0; j < 4; j++)
        bv[j] = *(const short8*)&Bsm[(wn + j * 16 + l15) * 64 + pc];
      #pragma unroll
      for (int i = 0; i < 4; i++)
        #pragma unroll
        for (int j = 0; j < 4; j++)
          acc[i][j] = MFMA(av[i], bv[j], acc[i][j]);
    }
  }

  #pragma unroll
  for (int j = 0; j < 4; j++) {
    int col = n0 + wn + j * 16 + l15;
    float bj = bias[col];
    #pragma unroll
    for (int i = 0; i < 4; i++) {
      #pragma unroll
      for (int r = 0; r < 4; r++) {
        int row = m0 + wm + i * 16 + quad * 4 + r;
        out[(size_t)row * 1024 + col] = acc[i][j][r] + bj;
      }
    }
  }
}

// ---------- launch ----------
extern "C" void kernel_launch(void* const* d_in, const int* in_sizes, int n_in,
                              void* d_out, int out_size, void* d_ws, size_t ws_size,
                              hipStream_t stream) {
  (void)in_sizes; (void)n_in; (void)out_size; (void)ws_size;
  const float* x     = (const float*)d_in[0];
  const int*   mask  = (const int*)d_in[1];
  const float* Wqkv  = (const float*)d_in[2];
  const float* Wproj = (const float*)d_in[3];
  const float* bproj = (const float*)d_in[4];
  float* out = (float*)d_out;
  char* ws = (char*)d_ws;

  size_t off = 0;
  u16* xb     = (u16*)(ws + off); off += 8192ull * 1024 * 2;   // x bf16 [8192][1024]
  u16* wqkvt  = (u16*)(ws + off); off += 3072ull * 1024 * 2;   // Wqkv^T bf16 [3072][1024]
  u16* wprojt = (u16*)(ws + off); off += 1024ull * 1024 * 2;   // Wproj^T bf16 [1024][1024]
  u16* qbuf   = (u16*)(ws + off); off += 8192ull * 1024 * 2;   // Q bf16 [8192][1024]
  u16* kcbuf  = (u16*)(ws + off); off += 4096ull * 2048 * 2;   // K compact [b][slot][1024]
  u16* vtcbuf = (u16*)(ws + off); off += 4096ull * 2048 * 2;   // V^T compact [b][d][slot]
  u16* aobuf  = (u16*)(ws + off); off += 8192ull * 1024 * 2;   // attn out bf16 [8192][1024]
  int* s2t    = (int*)(ws + off); off += 8192ull * 4;          // slot -> global token
  int* nkbuf  = (int*)(ws + off); off += 4 * 4;                // per-batch nk

  prep<<<9220, 256, 0, stream>>>(x, mask, Wqkv, Wproj, xb, wqkvt, wprojt, s2t, nkbuf);
  gemm_fused<<<1536, 256, 0, stream>>>(xb, wqkvt, s2t, nkbuf, qbuf, kcbuf, vtcbuf);
  attn_kernel<<<dim3(16, 4, 8), 256, 0, stream>>>(qbuf, kcbuf, vtcbuf, nkbuf, aobuf);
  gemm_proj<<<dim3(8, 64), 256, 0, stream>>>(aobuf, wprojt, bproj, out);
}

// Round 9
// 225.651 us; speedup vs baseline: 1.0637x; 1.0281x over previous
//
#include <hip/hip_runtime.h>

typedef unsigned short u16;
typedef unsigned int u32;
typedef unsigned long long u64;
typedef __attribute__((ext_vector_type(8))) short short8;
typedef __attribute__((ext_vector_type(4))) float f32x4;

#define MLOGC (-14426.95f)   /* -10000 * log2(e) */

// ---------- helpers ----------
__device__ __forceinline__ u16 f2bf(float f) {
  u32 u = __builtin_bit_cast(u32, f);
  u += 0x7fffu + ((u >> 16) & 1u);   // RNE
  return (u16)(u >> 16);
}

__device__ __forceinline__ float fexp2(float x) {
#if __has_builtin(__builtin_amdgcn_exp2f)
  return __builtin_amdgcn_exp2f(x);   // v_exp_f32
#else
  return exp2f(x);
#endif
}

// async global->LDS, 16B per lane. LDS dest is wave-uniform base + lane*16.
__device__ __forceinline__ void glds16(u16* lds, const u16* g) {
  __builtin_amdgcn_global_load_lds(
      (const __attribute__((address_space(1))) u32*)g,
      (__attribute__((address_space(3))) u32*)lds, 16, 0, 0);
}

#define MFMA(a, b, c) __builtin_amdgcn_mfma_f32_16x16x32_bf16((a), (b), (c), 0, 0, 0)

// LDS tile layout (XOR-swizzled), tile = [64 rows][64 u16 cols] = 8 KiB:
//   physical 16B-chunk slot p of row r holds logical col-chunk (p ^ (r&7)).
// b128 reads hit 8 distinct 16B regions per half-wave (4-way = b128 minimum).

// ---------- kernel 1: fused prep (x cvt | W transposes | mask scan) ----------
__global__ __launch_bounds__(256) void prep(const float* __restrict__ x,
                                            const int* __restrict__ mask,
                                            const float* __restrict__ Wqkv,
                                            const float* __restrict__ Wproj,
                                            u16* __restrict__ xb,
                                            u16* __restrict__ wqkvt,
                                            u16* __restrict__ wprojt,
                                            int* __restrict__ s2t,
                                            int* __restrict__ nkbuf) {
  __shared__ float tile[64][65];
  __shared__ int wtot[4];
  __shared__ int wbase[5];
  const int bid = blockIdx.x, t = threadIdx.x;

  if (bid < 8192) {                    // ---- role: x fp32 -> bf16 ----
    int i = bid * 256 + t;
    float4 v = ((const float4*)x)[i];
    union { u16 s[4]; u64 ll; } u;
    u.s[0] = f2bf(v.x); u.s[1] = f2bf(v.y); u.s[2] = f2bf(v.z); u.s[3] = f2bf(v.w);
    ((u64*)xb)[i] = u.ll;
    return;
  }
  if (bid < 9216) {                    // ---- role: W transpose+cvt ----
    const float* Wm; u16* Wt; int Cc, bj, bi;
    if (bid < 8960) { int tt = bid - 8192; Wm = Wqkv;  Wt = wqkvt;  Cc = 3072; bj = tt % 48; bi = tt / 48; }
    else            { int tt = bid - 8960; Wm = Wproj; Wt = wprojt; Cc = 1024; bj = tt & 15; bi = tt >> 4; }
    const int r = t >> 4, c4 = (t & 15) << 2;
    for (int rr = r; rr < 64; rr += 16) {
      float4 v = *(const float4*)&Wm[(size_t)(bi * 64 + rr) * Cc + bj * 64 + c4];
      tile[rr][c4] = v.x; tile[rr][c4 + 1] = v.y; tile[rr][c4 + 2] = v.z; tile[rr][c4 + 3] = v.w;
    }
    __syncthreads();
    for (int rr = r; rr < 64; rr += 16) {
      union { u16 s[4]; u64 ll; } u;
      u.s[0] = f2bf(tile[c4][rr]);
      u.s[1] = f2bf(tile[c4 + 1][rr]);
      u.s[2] = f2bf(tile[c4 + 2][rr]);
      u.s[3] = f2bf(tile[c4 + 3][rr]);
      *(u64*)&Wt[(size_t)(bj * 64 + rr) * 1024 + bi * 64 + c4] = u.ll;
    }
    return;
  }
  // ---- role: per-batch stable partition of key tokens ----
  const int b = bid - 9216;
  const int lane = t & 63, w = t >> 6;
  int m8[8], c = 0;
  #pragma unroll
  for (int j = 0; j < 8; j++) {
    m8[j] = (mask[b * 2048 + t * 8 + j] == 1);
    c += m8[j];
  }
  int incl = c;
  #pragma unroll
  for (int off = 1; off < 64; off <<= 1) {
    int v = __shfl_up(incl, off);
    if (lane >= off) incl += v;
  }
  if (lane == 63) wtot[w] = incl;
  __syncthreads();
  if (t == 0) {
    int s = 0;
    for (int i = 0; i < 4; i++) { wbase[i] = s; s += wtot[i]; }
    wbase[4] = s;
  }
  __syncthreads();
  const int nk = wbase[4];
  int urun = wbase[w] + incl - c;
  #pragma unroll
  for (int j = 0; j < 8; j++) {
    int tok = t * 8 + j;
    int slot = m8[j] ? urun : nk + (tok - urun);
    s2t[b * 2048 + slot] = b * 2048 + tok;
    urun += m8[j];
  }
  if (t == 0) nkbuf[b] = nk;
}

// ---------- kernel 2: fused Q/K/V GEMM, flattened grid, compacted K/V ----------
__global__ __launch_bounds__(256, 4) void gemm_fused(const u16* __restrict__ xb,
                                                     const u16* __restrict__ wqkvt,
                                                     const int* __restrict__ s2t,
                                                     const int* __restrict__ nkbuf,
                                                     u16* __restrict__ qbuf,
                                                     u16* __restrict__ kc,
                                                     u16* __restrict__ vtc) {
  __shared__ u16 Asm[128 * 64];
  __shared__ u16 Bsm[128 * 64];
  const int bid = blockIdx.x;
  const int role = bid >> 9;            // 0=Q 1=K 2=V
  const int sub = bid & 511;
  const int tid = threadIdx.x, lane = tid & 63, w = tid >> 6;
  const int quad = lane >> 4, l15 = lane & 15;
  const int wm = (w >> 1) * 64, wn = (w & 1) * 64;
  const int srow = lane >> 3;
  const int gcc = ((lane & 7) ^ srow) * 8;
  const int rx8 = (l15 & 7);

  int m0, n0;
  const u16 *Asrc, *Bsrc;
  if (role == 2) { m0 = (sub & 7) * 128; n0 = (sub >> 3) * 128; }
  else           { m0 = (sub >> 3) * 128; n0 = (sub & 7) * 128; }
  if (role == 1 && (m0 & 2047) >= nkbuf[m0 >> 11]) return;
  if (role == 2 && (n0 & 2047) >= nkbuf[n0 >> 11]) return;

  // per-lane source row ids for the 4 staged chunks
  int arow[4], brow[4];
  #pragma unroll
  for (int c = 0; c < 4; ++c) {
    int rit = (w * 4 + c) * 8 + srow;   // row within the 128-tile
    if (role == 0)      { arow[c] = m0 + rit;            brow[c] = n0 + rit; }
    else if (role == 1) { arow[c] = s2t[m0 + rit];       brow[c] = 1024 + n0 + rit; }
    else                { arow[c] = 2048 + m0 + rit;     brow[c] = s2t[n0 + rit]; }
  }
  Asrc = (role == 2) ? wqkvt : xb;
  Bsrc = (role == 2) ? xb : wqkvt;

  f32x4 acc[4][4];
  #pragma unroll
  for (int i = 0; i < 4; i++)
    #pragma unroll
    for (int j = 0; j < 4; j++)
      #pragma unroll
      for (int r = 0; r < 4; r++) acc[i][j][r] = 0.f;

  for (int kt = 0; kt < 1024; kt += 64) {
    __syncthreads();
    #pragma unroll
    for (int c = 0; c < 4; ++c) {
      int chunk = w * 4 + c;
      glds16(&Asm[chunk * 512], &Asrc[(size_t)arow[c] * 1024 + kt + gcc]);
      glds16(&Bsm[chunk * 512], &Bsrc[(size_t)brow[c] * 1024 + kt + gcc]);
    }
    __syncthreads();
    #pragma unroll
    for (int ks = 0; ks < 2; ++ks) {
      int pc = ((ks * 4 + quad) ^ rx8) * 8;
      short8 av[4], bv[4];
      #pragma unroll
      for (int i = 0; i < 4; i++)
        av[i] = *(const short8*)&Asm[(wm + i * 16 + l15) * 64 + pc];
      #pragma unroll
      for (int j = 0; j < 4; j++)
        bv[j] = *(const short8*)&Bsm[(wn + j * 16 + l15) * 64 + pc];
      #pragma unroll
      for (int i = 0; i < 4; i++)
        #pragma unroll
        for (int j = 0; j < 4; j++)
          acc[i][j] = MFMA(av[i], bv[j], acc[i][j]);
    }
  }

  if (role == 2) {
    #pragma unroll
    for (int j = 0; j < 4; j++) {
      int col = n0 + wn + j * 16 + l15;           // global slot 0..8191
      int bb = col >> 11, sl = col & 2047;
      #pragma unroll
      for (int i = 0; i < 4; i++)
        #pragma unroll
        for (int r = 0; r < 4; r++) {
          int row = m0 + wm + i * 16 + quad * 4 + r;   // d in 0..1023
          vtc[(size_t)(bb * 1024 + row) * 2048 + sl] = f2bf(acc[i][j][r]);
        }
    }
  } else {
    u16* dst = (role == 0) ? qbuf : kc;   // rows are tokens (Q) or slots (K); both dense
    #pragma unroll
    for (int i = 0; i < 4; i++)
      #pragma unroll
      for (int j = 0; j < 4; j++) {
        int col = n0 + wn + j * 16 + l15;
        #pragma unroll
        for (int r = 0; r < 4; r++) {
          int row = m0 + wm + i * 16 + quad * 4 + r;
          dst[(size_t)row * 1024 + col] = f2bf(acc[i][j][r]);
        }
      }
  }
}

// ---------- kernel 3: flash attention, register-resident P (no LDS round-trip) ----------
// S^T = K·Q^T (A=K, B=Q): C-layout gives lane q=l15, keys=(j,quad,r) — already
// PV's A-operand ownership. Key permutation π(ρ)=(j&1)*32+quad*8+(j>>1)*4+r is
// baked into WHICH kc row each K-staging lane fetches (glds16 src is per-lane;
// full 128B rows so coalescing is unchanged). V stays linear. P: exp -> +0x8000
// -> v_perm pack -> MFMA A-frag, all in registers. LDS = K+V tiles only (16 KB).
__global__ __launch_bounds__(256, 2) void attn_kernel(const u16* __restrict__ q,
                                                      const u16* __restrict__ kc,
                                                      const u16* __restrict__ vtc,
                                                      const int* __restrict__ nkbuf,
                                                      u16* __restrict__ ao) {
  __shared__ u16 Ksm[64 * 64];          // π-permuted key rows, swizzled cols (d)
  __shared__ u16 Vsm[64 * 64];          // [d][k_local] linear keys, swizzled
  const int h = blockIdx.x, b = blockIdx.y, qt = blockIdx.z;
  const int tid = threadIdx.x, lane = tid & 63, w = tid >> 6;
  const int quad = lane >> 4, l15 = lane & 15;
  const int q0 = qt * 256 + w * 64;     // wave's q base within batch
  const int srow = lane >> 3;
  const int gcc = ((lane & 7) ^ srow) * 8;
  const int rx8 = (l15 & 7);
  const float C1 = 0.18033688f;         // 0.125 * log2(e)
  const int nk = nkbuf[b];
  const int ntiles = (nk + 63) >> 6;
  const int quad8 = quad * 8;

  // staging rows + π for K source
  int vrow[2], prow[2];
  #pragma unroll
  for (int c = 0; c < 2; ++c) {
    int row = (w * 2 + c) * 8 + srow;
    vrow[c] = row;
    prow[c] = ((row >> 4) & 1) * 32 + ((row >> 2) & 3) * 8 + ((row >> 5) & 1) * 4 + (row & 3);
  }

  // Q fragments (B-operand): n=q=l15(+16i), k=d=quad*8+j (+32ks)
  short8 qf[4][2];
  #pragma unroll
  for (int i = 0; i < 4; i++)
    #pragma unroll
    for (int ks = 0; ks < 2; ks++)
      qf[i][ks] = *(const short8*)&q[(size_t)(b * 2048 + q0 + i * 16 + l15) * 1024 +
                                     h * 64 + ks * 32 + quad * 8];

  f32x4 o[4][4];
  float lsum[4];
  #pragma unroll
  for (int i = 0; i < 4; i++) {
    lsum[i] = 0.f;
    #pragma unroll
    for (int jd = 0; jd < 4; jd++)
      #pragma unroll
      for (int r = 0; r < 4; r++) o[i][jd][r] = 0.f;
  }

  for (int t = 0; t < ntiles; ++t) {
    const int k0 = t * 64;
    __syncthreads();
    #pragma unroll
    for (int c = 0; c < 2; ++c) {
      int chunk = w * 2 + c;
      glds16(&Ksm[chunk * 512], &kc[(size_t)(b * 2048 + k0 + prow[c]) * 1024 + h * 64 + gcc]);
      glds16(&Vsm[chunk * 512], &vtc[(size_t)(b * 1024 + h * 64 + vrow[c]) * 2048 + k0 + gcc]);
    }
    __syncthreads();

    // S^T = K·Q^T : s[j][i] rows = π-keys (j*16+quad*4+r), cols = q (i*16+l15)
    f32x4 s[4][4];
    #pragma unroll
    for (int j = 0; j < 4; j++)
      #pragma unroll
      for (int i = 0; i < 4; i++)
        #pragma unroll
        for (int r = 0; r < 4; r++) s[j][i][r] = 0.f;
    #pragma unroll
    for (int ks = 0; ks < 2; ks++) {
      int pc = ((ks * 4 + quad) ^ rx8) * 8;
      short8 kf[4];
      #pragma unroll
      for (int j = 0; j < 4; j++)
        kf[j] = *(const short8*)&Ksm[(j * 16 + l15) * 64 + pc];
      #pragma unroll
      for (int j = 0; j < 4; j++)
        #pragma unroll
        for (int i = 0; i < 4; i++) s[j][i] = MFMA(kf[j], qf[i][ks], s[j][i]);
    }

    // additive mask in key space: slot = k0 + π(j,quad,r); tail tile only
    float mlog[4][4];
    if (k0 + 64 <= nk) {
      #pragma unroll
      for (int j = 0; j < 4; j++)
        #pragma unroll
        for (int r = 0; r < 4; r++) mlog[j][r] = 0.f;
    } else {
      #pragma unroll
      for (int j = 0; j < 4; j++)
        #pragma unroll
        for (int r = 0; r < 4; r++) {
          int slot = k0 + (j & 1) * 32 + quad8 + (j >> 1) * 4 + r;
          mlog[j][r] = (slot < nk) ? 0.f : MLOGC;
        }
    }

    // exp -> register P (A-frags) + per-lane row sums
    short8 pf[4][2];
    #pragma unroll
    for (int i = 0; i < 4; i++) {
      float p[4][4];
      float ps = 0.f;
      #pragma unroll
      for (int j = 0; j < 4; j++)
        #pragma unroll
        for (int r = 0; r < 4; r++) {
          p[j][r] = fexp2(__builtin_fmaf(s[j][i][r], C1, mlog[j][r]));
          ps += p[j][r];
        }
      lsum[i] += ps;
      #pragma unroll
      for (int ks = 0; ks < 2; ks++) {
        union { u32 u[4]; short8 v; } pk;
        u32 a0 = __builtin_bit_cast(u32, p[ks][0]) + 0x8000u;
        u32 a1 = __builtin_bit_cast(u32, p[ks][1]) + 0x8000u;
        u32 a2 = __builtin_bit_cast(u32, p[ks][2]) + 0x8000u;
        u32 a3 = __builtin_bit_cast(u32, p[ks][3]) + 0x8000u;
        u32 b0 = __builtin_bit_cast(u32, p[ks + 2][0]) + 0x8000u;
        u32 b1 = __builtin_bit_cast(u32, p[ks + 2][1]) + 0x8000u;
        u32 b2 = __builtin_bit_cast(u32, p[ks + 2][2]) + 0x8000u;
        u32 b3 = __builtin_bit_cast(u32, p[ks + 2][3]) + 0x8000u;
        pk.u[0] = __builtin_amdgcn_perm(a1, a0, 0x07060302u);
        pk.u[1] = __builtin_amdgcn_perm(a3, a2, 0x07060302u);
        pk.u[2] = __builtin_amdgcn_perm(b1, b0, 0x07060302u);
        pk.u[3] = __builtin_amdgcn_perm(b3, b2, 0x07060302u);
        pf[i][ks] = pk.v;
      }
    }

    // O += P·V  (A=P regs, B=V linear)
    #pragma unroll
    for (int ks = 0; ks < 2; ks++) {
      int pcv = ((ks * 4 + quad) ^ rx8) * 8;
      short8 vf[4];
      #pragma unroll
      for (int jd = 0; jd < 4; jd++)
        vf[jd] = *(const short8*)&Vsm[(jd * 16 + l15) * 64 + pcv];
      #pragma unroll
      for (int i = 0; i < 4; i++)
        #pragma unroll
        for (int jd = 0; jd < 4; jd++) o[i][jd] = MFMA(pf[i][ks], vf[jd], o[i][jd]);
    }
  }

  // reduce lsum across the 4 quads (lanes sharing l15), then normalize + store.
  // lsum[i] lives at q=i*16+l15; o rows are q=i*16+quad*4+r -> realign via shfl.
  #pragma unroll
  for (int i = 0; i < 4; i++) {
    float l = lsum[i];
    l += __shfl_xor(l, 16);
    l += __shfl_xor(l, 32);
    lsum[i] = l;
  }
  #pragma unroll
  for (int i = 0; i < 4; i++)
    #pragma unroll
    for (int r = 0; r < 4; r++) {
      float inv = 1.f / __shfl(lsum[i], (lane & 48) | (quad * 4 + r));
      size_t row = (size_t)(b * 2048 + q0 + i * 16 + quad * 4 + r);
      #pragma unroll
      for (int jd = 0; jd < 4; jd++)
        ao[row * 1024 + h * 64 + jd * 16 + l15] = f2bf(o[i][jd][r] * inv);
    }
}

// ---------- kernel 4: output projection + bias ----------
__global__ __launch_bounds__(256, 3) void gemm_proj(const u16* __restrict__ A,
                                                    const u16* __restrict__ Bt,
                                                    const float* __restrict__ bias,
                                                    float* __restrict__ out) {
  __shared__ u16 Asm[128 * 64];
  __shared__ u16 Bsm[128 * 64];
  const int tid = threadIdx.x, lane = tid & 63, w = tid >> 6;
  const int quad = lane >> 4, l15 = lane & 15;
  const int m0 = blockIdx.y * 128, n0 = blockIdx.x * 128;
  const int wm = (w >> 1) * 64, wn = (w & 1) * 64;
  const int srow = lane >> 3;
  const int gcc = ((lane & 7) ^ srow) * 8;
  const int rx8 = (l15 & 7);
  f32x4 acc[4][4];
  #pragma unroll
  for (int i = 0; i < 4; i++)
    #pragma unroll
    for (int j = 0; j < 4; j++)
      #pragma unroll
      for (int r = 0; r < 4; r++) acc[i][j][r] = 0.f;

  for (int kt = 0; kt < 1024; kt += 64) {
    __syncthreads();
    #pragma unroll
    for (int c = 0; c < 4; ++c) {
      int chunk = w * 4 + c;
      int row = chunk * 8 + srow;
      glds16(&Asm[chunk * 512], &A[(size_t)(m0 + row) * 1024 + kt + gcc]);
      glds16(&Bsm[chunk * 512], &Bt[(size_t)(n0 + row) * 1024 + kt + gcc]);
    }
    __syncthreads();
    #pragma unroll
    for (int ks = 0; ks < 2; ++ks) {
      int pc = ((ks * 4 + quad) ^ rx8) * 8;
      short8 av[4], bv[4];
      #pragma unroll
      for (int i = 0; i < 4; i++)
        av[i] = *(const short8*)&Asm[(wm + i * 16 + l15) * 64 + pc];
      #pragma unroll
      for (int j = 0; j < 4; j++)
        bv[j] = *(const short8*)&Bsm[(wn + j * 16 + l15) * 64 + pc];
      #pragma unroll
      for (int i = 0; i < 4; i++)
        #pragma unroll
        for (int j = 0; j < 4; j++)
          acc[i][j] = MFMA(av[i], bv[j], acc[i][j]);
    }
  }

  #pragma unroll
  for (int j = 0; j < 4; j++) {
    int col = n0 + wn + j * 16 + l15;
    float bj = bias[col];
    #pragma unroll
    for (int i = 0; i < 4; i++) {
      #pragma unroll
      for (int r = 0; r < 4; r++) {
        int row = m0 + wm + i * 16 + quad * 4 + r;
        out[(size_t)row * 1024 + col] = acc[i][j][r] + bj;
      }
    }
  }
}

// ---------- launch ----------
extern "C" void kernel_launch(void* const* d_in, const int* in_sizes, int n_in,
                              void* d_out, int out_size, void* d_ws, size_t ws_size,
                              hipStream_t stream) {
  (void)in_sizes; (void)n_in; (void)out_size; (void)ws_size;
  const float* x     = (const float*)d_in[0];
  const int*   mask  = (const int*)d_in[1];
  const float* Wqkv  = (const float*)d_in[2];
  const float* Wproj = (const float*)d_in[3];
  const float* bproj = (const float*)d_in[4];
  float* out = (float*)d_out;
  char* ws = (char*)d_ws;

  size_t off = 0;
  u16* xb     = (u16*)(ws + off); off += 8192ull * 1024 * 2;   // x bf16 [8192][1024]
  u16* wqkvt  = (u16*)(ws + off); off += 3072ull * 1024 * 2;   // Wqkv^T bf16 [3072][1024]
  u16* wprojt = (u16*)(ws + off); off += 1024ull * 1024 * 2;   // Wproj^T bf16 [1024][1024]
  u16* qbuf   = (u16*)(ws + off); off += 8192ull * 1024 * 2;   // Q bf16 [8192][1024]
  u16* kcbuf  = (u16*)(ws + off); off += 4096ull * 2048 * 2;   // K compact [b][slot][1024]
  u16* vtcbuf = (u16*)(ws + off); off += 4096ull * 2048 * 2;   // V^T compact [b][d][slot]
  u16* aobuf  = (u16*)(ws + off); off += 8192ull * 1024 * 2;   // attn out bf16 [8192][1024]
  int* s2t    = (int*)(ws + off); off += 8192ull * 4;          // slot -> global token
  int* nkbuf  = (int*)(ws + off); off += 4 * 4;                // per-batch nk

  prep<<<9220, 256, 0, stream>>>(x, mask, Wqkv, Wproj, xb, wqkvt, wprojt, s2t, nkbuf);
  gemm_fused<<<1536, 256, 0, stream>>>(xb, wqkvt, s2t, nkbuf, qbuf, kcbuf, vtcbuf);
  attn_kernel<<<dim3(16, 4, 8), 256, 0, stream>>>(qbuf, kcbuf, vtcbuf, nkbuf, aobuf);
  gemm_proj<<<dim3(8, 64), 256, 0, stream>>>(aobuf, wprojt, bproj, out);
}

// Round 10
// 217.917 us; speedup vs baseline: 1.1015x; 1.0355x over previous
//
#include <hip/hip_runtime.h>

typedef unsigned short u16;
typedef unsigned int u32;
typedef unsigned long long u64;
typedef __attribute__((ext_vector_type(8))) short short8;
typedef __attribute__((ext_vector_type(4))) float f32x4;

#define QSCALE 0.18033688f   /* 0.125 * log2(e), folded into Q at projection */

// ---------- helpers ----------
__device__ __forceinline__ u16 f2bf(float f) {
  u32 u = __builtin_bit_cast(u32, f);
  u += 0x7fffu + ((u >> 16) & 1u);   // RNE
  return (u16)(u >> 16);
}

__device__ __forceinline__ float fexp2(float x) {
#if __has_builtin(__builtin_amdgcn_exp2f)
  return __builtin_amdgcn_exp2f(x);   // v_exp_f32
#else
  return exp2f(x);
#endif
}

// async global->LDS, 16B per lane. LDS dest is wave-uniform base + lane*16.
__device__ __forceinline__ void glds16(u16* lds, const u16* g) {
  __builtin_amdgcn_global_load_lds(
      (const __attribute__((address_space(1))) u32*)g,
      (__attribute__((address_space(3))) u32*)lds, 16, 0, 0);
}

#define MFMA(a, b, c) __builtin_amdgcn_mfma_f32_16x16x32_bf16((a), (b), (c), 0, 0, 0)

// LDS tile layout (XOR-swizzled), tile = [64 rows][64 u16 cols] = 8 KiB:
//   physical 16B-chunk slot p of row r holds logical col-chunk (p ^ (r&7)).
// b128 reads hit 8 distinct 16B regions per half-wave (4-way = b128 minimum).

// ---------- kernel 1: fused prep (x cvt | W transposes | mask scan) ----------
__global__ __launch_bounds__(256) void prep(const float* __restrict__ x,
                                            const int* __restrict__ mask,
                                            const float* __restrict__ Wqkv,
                                            const float* __restrict__ Wproj,
                                            u16* __restrict__ xb,
                                            u16* __restrict__ wqkvt,
                                            u16* __restrict__ wprojt,
                                            int* __restrict__ s2t,
                                            int* __restrict__ nkbuf) {
  __shared__ float tile[64][65];
  __shared__ int wtot[4];
  __shared__ int wbase[5];
  const int bid = blockIdx.x, t = threadIdx.x;

  if (bid < 8192) {                    // ---- role: x fp32 -> bf16 ----
    int i = bid * 256 + t;
    float4 v = ((const float4*)x)[i];
    union { u16 s[4]; u64 ll; } u;
    u.s[0] = f2bf(v.x); u.s[1] = f2bf(v.y); u.s[2] = f2bf(v.z); u.s[3] = f2bf(v.w);
    ((u64*)xb)[i] = u.ll;
    return;
  }
  if (bid < 9216) {                    // ---- role: W transpose+cvt ----
    const float* Wm; u16* Wt; int Cc, bj, bi;
    if (bid < 8960) { int tt = bid - 8192; Wm = Wqkv;  Wt = wqkvt;  Cc = 3072; bj = tt % 48; bi = tt / 48; }
    else            { int tt = bid - 8960; Wm = Wproj; Wt = wprojt; Cc = 1024; bj = tt & 15; bi = tt >> 4; }
    const int r = t >> 4, c4 = (t & 15) << 2;
    for (int rr = r; rr < 64; rr += 16) {
      float4 v = *(const float4*)&Wm[(size_t)(bi * 64 + rr) * Cc + bj * 64 + c4];
      tile[rr][c4] = v.x; tile[rr][c4 + 1] = v.y; tile[rr][c4 + 2] = v.z; tile[rr][c4 + 3] = v.w;
    }
    __syncthreads();
    for (int rr = r; rr < 64; rr += 16) {
      union { u16 s[4]; u64 ll; } u;
      u.s[0] = f2bf(tile[c4][rr]);
      u.s[1] = f2bf(tile[c4 + 1][rr]);
      u.s[2] = f2bf(tile[c4 + 2][rr]);
      u.s[3] = f2bf(tile[c4 + 3][rr]);
      *(u64*)&Wt[(size_t)(bj * 64 + rr) * 1024 + bi * 64 + c4] = u.ll;
    }
    return;
  }
  // ---- role: per-batch stable partition of key tokens ----
  const int b = bid - 9216;
  const int lane = t & 63, w = t >> 6;
  int m8[8], c = 0;
  #pragma unroll
  for (int j = 0; j < 8; j++) {
    m8[j] = (mask[b * 2048 + t * 8 + j] == 1);
    c += m8[j];
  }
  int incl = c;
  #pragma unroll
  for (int off = 1; off < 64; off <<= 1) {
    int v = __shfl_up(incl, off);
    if (lane >= off) incl += v;
  }
  if (lane == 63) wtot[w] = incl;
  __syncthreads();
  if (t == 0) {
    int s = 0;
    for (int i = 0; i < 4; i++) { wbase[i] = s; s += wtot[i]; }
    wbase[4] = s;
  }
  __syncthreads();
  const int nk = wbase[4];
  int urun = wbase[w] + incl - c;
  #pragma unroll
  for (int j = 0; j < 8; j++) {
    int tok = t * 8 + j;
    int slot = m8[j] ? urun : nk + (tok - urun);
    s2t[b * 2048 + slot] = b * 2048 + tok;
    urun += m8[j];
  }
  if (t == 0) nkbuf[b] = nk;
}

// ---------- kernel 2: fused Q/K/V GEMM, flattened grid, compacted K/V ----------
// Q-role epilogue pre-multiplies by QSCALE so attention's exp is bare exp2(s).
__global__ __launch_bounds__(256, 4) void gemm_fused(const u16* __restrict__ xb,
                                                     const u16* __restrict__ wqkvt,
                                                     const int* __restrict__ s2t,
                                                     const int* __restrict__ nkbuf,
                                                     u16* __restrict__ qbuf,
                                                     u16* __restrict__ kc,
                                                     u16* __restrict__ vtc) {
  __shared__ u16 Asm[128 * 64];
  __shared__ u16 Bsm[128 * 64];
  const int bid = blockIdx.x;
  const int role = bid >> 9;            // 0=Q 1=K 2=V
  const int sub = bid & 511;
  const int tid = threadIdx.x, lane = tid & 63, w = tid >> 6;
  const int quad = lane >> 4, l15 = lane & 15;
  const int wm = (w >> 1) * 64, wn = (w & 1) * 64;
  const int srow = lane >> 3;
  const int gcc = ((lane & 7) ^ srow) * 8;
  const int rx8 = (l15 & 7);

  int m0, n0;
  const u16 *Asrc, *Bsrc;
  if (role == 2) { m0 = (sub & 7) * 128; n0 = (sub >> 3) * 128; }
  else           { m0 = (sub >> 3) * 128; n0 = (sub & 7) * 128; }
  if (role == 1 && (m0 & 2047) >= nkbuf[m0 >> 11]) return;
  if (role == 2 && (n0 & 2047) >= nkbuf[n0 >> 11]) return;

  // per-lane source row ids for the 4 staged chunks
  int arow[4], brow[4];
  #pragma unroll
  for (int c = 0; c < 4; ++c) {
    int rit = (w * 4 + c) * 8 + srow;   // row within the 128-tile
    if (role == 0)      { arow[c] = m0 + rit;            brow[c] = n0 + rit; }
    else if (role == 1) { arow[c] = s2t[m0 + rit];       brow[c] = 1024 + n0 + rit; }
    else                { arow[c] = 2048 + m0 + rit;     brow[c] = s2t[n0 + rit]; }
  }
  Asrc = (role == 2) ? wqkvt : xb;
  Bsrc = (role == 2) ? xb : wqkvt;

  f32x4 acc[4][4];
  #pragma unroll
  for (int i = 0; i < 4; i++)
    #pragma unroll
    for (int j = 0; j < 4; j++)
      #pragma unroll
      for (int r = 0; r < 4; r++) acc[i][j][r] = 0.f;

  for (int kt = 0; kt < 1024; kt += 64) {
    __syncthreads();
    #pragma unroll
    for (int c = 0; c < 4; ++c) {
      int chunk = w * 4 + c;
      glds16(&Asm[chunk * 512], &Asrc[(size_t)arow[c] * 1024 + kt + gcc]);
      glds16(&Bsm[chunk * 512], &Bsrc[(size_t)brow[c] * 1024 + kt + gcc]);
    }
    __syncthreads();
    #pragma unroll
    for (int ks = 0; ks < 2; ++ks) {
      int pc = ((ks * 4 + quad) ^ rx8) * 8;
      short8 av[4], bv[4];
      #pragma unroll
      for (int i = 0; i < 4; i++)
        av[i] = *(const short8*)&Asm[(wm + i * 16 + l15) * 64 + pc];
      #pragma unroll
      for (int j = 0; j < 4; j++)
        bv[j] = *(const short8*)&Bsm[(wn + j * 16 + l15) * 64 + pc];
      #pragma unroll
      for (int i = 0; i < 4; i++)
        #pragma unroll
        for (int j = 0; j < 4; j++)
          acc[i][j] = MFMA(av[i], bv[j], acc[i][j]);
    }
  }

  if (role == 2) {
    #pragma unroll
    for (int j = 0; j < 4; j++) {
      int col = n0 + wn + j * 16 + l15;           // global slot 0..8191
      int bb = col >> 11, sl = col & 2047;
      #pragma unroll
      for (int i = 0; i < 4; i++)
        #pragma unroll
        for (int r = 0; r < 4; r++) {
          int row = m0 + wm + i * 16 + quad * 4 + r;   // d in 0..1023
          vtc[(size_t)(bb * 1024 + row) * 2048 + sl] = f2bf(acc[i][j][r]);
        }
    }
  } else {
    u16* dst = (role == 0) ? qbuf : kc;
    const float sc = (role == 0) ? QSCALE : 1.f;
    #pragma unroll
    for (int i = 0; i < 4; i++)
      #pragma unroll
      for (int j = 0; j < 4; j++) {
        int col = n0 + wn + j * 16 + l15;
        #pragma unroll
        for (int r = 0; r < 4; r++) {
          int row = m0 + wm + i * 16 + quad * 4 + r;
          dst[(size_t)row * 1024 + col] = f2bf(acc[i][j][r] * sc);
        }
      }
  }
}

// ---------- kernel 3: flash attention, register P, BK=128, MFMA row-sums ----------
// S^T = K·Q^T; P stays in registers (v_perm pack). Two 64-key sub-tiles staged
// per barrier pair (32 KB LDS) — half the barriers of BK=64. Row sums via
// MFMA(pf, ones): D rows are quad*4+r = o's rows, so no epilogue shuffles and
// the denominator is bit-consistent with the PV numerator. Q is pre-scaled by
// QSCALE at projection, so p = exp2(s) (tail: cndmask to exact 0).
__global__ __launch_bounds__(256, 2) void attn_kernel(const u16* __restrict__ q,
                                                      const u16* __restrict__ kc,
                                                      const u16* __restrict__ vtc,
                                                      const int* __restrict__ nkbuf,
                                                      u16* __restrict__ ao) {
  __shared__ u16 Ksm[2][64 * 64];       // π-permuted key rows, swizzled cols (d)
  __shared__ u16 Vsm[2][64 * 64];       // [d][k_local] linear keys, swizzled
  const int h = blockIdx.x, b = blockIdx.y, qt = blockIdx.z;
  const int tid = threadIdx.x, lane = tid & 63, w = tid >> 6;
  const int quad = lane >> 4, l15 = lane & 15;
  const int q0 = qt * 256 + w * 64;     // wave's q base within batch
  const int srow = lane >> 3;
  const int gcc = ((lane & 7) ^ srow) * 8;
  const int rx8 = (l15 & 7);
  const int nk = nkbuf[b];
  const int nt2 = (nk + 127) >> 7;
  const int quad8 = quad * 8;

  // staging rows + π for K source
  int vrow[2], prow[2];
  #pragma unroll
  for (int c = 0; c < 2; ++c) {
    int row = (w * 2 + c) * 8 + srow;
    vrow[c] = row;
    prow[c] = ((row >> 4) & 1) * 32 + ((row >> 2) & 3) * 8 + ((row >> 5) & 1) * 4 + (row & 3);
  }

  // ones B-fragment (bf16 1.0 splat) for MFMA row-sums
  short8 ones;
  #pragma unroll
  for (int z = 0; z < 8; z++) ones[z] = (short)0x3F80;

  // Q fragments (B-operand): n=q=l15(+16i), k=d=quad*8+j (+32ks)
  short8 qf[4][2];
  #pragma unroll
  for (int i = 0; i < 4; i++)
    #pragma unroll
    for (int ks = 0; ks < 2; ks++)
      qf[i][ks] = *(const short8*)&q[(size_t)(b * 2048 + q0 + i * 16 + l15) * 1024 +
                                     h * 64 + ks * 32 + quad * 8];

  f32x4 o[4][4], osum[4];
  #pragma unroll
  for (int i = 0; i < 4; i++) {
    #pragma unroll
    for (int r = 0; r < 4; r++) osum[i][r] = 0.f;
    #pragma unroll
    for (int jd = 0; jd < 4; jd++)
      #pragma unroll
      for (int r = 0; r < 4; r++) o[i][jd][r] = 0.f;
  }

#define SUBTILE(st_, kbase_)                                                           \
  {                                                                                    \
    f32x4 s[4][4];                                                                     \
    _Pragma("unroll") for (int j = 0; j < 4; j++)                                      \
      _Pragma("unroll") for (int i = 0; i < 4; i++)                                    \
        _Pragma("unroll") for (int r = 0; r < 4; r++) s[j][i][r] = 0.f;                \
    _Pragma("unroll") for (int ks = 0; ks < 2; ks++) {                                 \
      int pc = ((ks * 4 + quad) ^ rx8) * 8;                                            \
      short8 kf[4];                                                                    \
      _Pragma("unroll") for (int j = 0; j < 4; j++)                                    \
        kf[j] = *(const short8*)&Ksm[st_][(j * 16 + l15) * 64 + pc];                   \
      _Pragma("unroll") for (int j = 0; j < 4; j++)                                    \
        _Pragma("unroll") for (int i = 0; i < 4; i++)                                  \
          s[j][i] = MFMA(kf[j], qf[i][ks], s[j][i]);                                   \
    }                                                                                  \
    const bool tail = ((kbase_) + 64 > nk);                                            \
    short8 pf[4][2];                                                                   \
    _Pragma("unroll") for (int i = 0; i < 4; i++) {                                    \
      float p[4][4];                                                                   \
      if (!tail) {                                                                     \
        _Pragma("unroll") for (int j = 0; j < 4; j++)                                  \
          _Pragma("unroll") for (int r = 0; r < 4; r++)                                \
            p[j][r] = fexp2(s[j][i][r]);                                               \
      } else {                                                                         \
        _Pragma("unroll") for (int j = 0; j < 4; j++)                                  \
          _Pragma("unroll") for (int r = 0; r < 4; r++) {                              \
            int slot = (kbase_) + (j & 1) * 32 + quad8 + (j >> 1) * 4 + r;             \
            float e = fexp2(s[j][i][r]);                                               \
            p[j][r] = (slot < nk) ? e : 0.f;                                           \
          }                                                                            \
      }                                                                                \
      _Pragma("unroll") for (int ks = 0; ks < 2; ks++) {                               \
        union { u32 u[4]; short8 v; } pk;                                              \
        u32 a0 = __builtin_bit_cast(u32, p[ks][0]) + 0x8000u;                          \
        u32 a1 = __builtin_bit_cast(u32, p[ks][1]) + 0x8000u;                          \
        u32 a2 = __builtin_bit_cast(u32, p[ks][2]) + 0x8000u;                          \
        u32 a3 = __builtin_bit_cast(u32, p[ks][3]) + 0x8000u;                          \
        u32 b0 = __builtin_bit_cast(u32, p[ks + 2][0]) + 0x8000u;                      \
        u32 b1 = __builtin_bit_cast(u32, p[ks + 2][1]) + 0x8000u;                      \
        u32 b2 = __builtin_bit_cast(u32, p[ks + 2][2]) + 0x8000u;                      \
        u32 b3 = __builtin_bit_cast(u32, p[ks + 2][3]) + 0x8000u;                      \
        pk.u[0] = __builtin_amdgcn_perm(a1, a0, 0x07060302u);                          \
        pk.u[1] = __builtin_amdgcn_perm(a3, a2, 0x07060302u);                          \
        pk.u[2] = __builtin_amdgcn_perm(b1, b0, 0x07060302u);                          \
        pk.u[3] = __builtin_amdgcn_perm(b3, b2, 0x07060302u);                          \
        pf[i][ks] = pk.v;                                                              \
      }                                                                                \
    }                                                                                  \
    _Pragma("unroll") for (int ks = 0; ks < 2; ks++) {                                 \
      int pcv = ((ks * 4 + quad) ^ rx8) * 8;                                           \
      short8 vf[4];                                                                    \
      _Pragma("unroll") for (int jd = 0; jd < 4; jd++)                                 \
        vf[jd] = *(const short8*)&Vsm[st_][(jd * 16 + l15) * 64 + pcv];                \
      _Pragma("unroll") for (int i = 0; i < 4; i++) {                                  \
        osum[i] = MFMA(pf[i][ks], ones, osum[i]);                                      \
        _Pragma("unroll") for (int jd = 0; jd < 4; jd++)                               \
          o[i][jd] = MFMA(pf[i][ks], vf[jd], o[i][jd]);                                \
      }                                                                                \
    }                                                                                  \
  }

  for (int t = 0; t < nt2; ++t) {
    const int k0 = t * 128;
    __syncthreads();
    #pragma unroll
    for (int c = 0; c < 2; ++c) {
      int chunk = w * 2 + c;
      glds16(&Ksm[0][chunk * 512],
             &kc[(size_t)(b * 2048 + k0 + prow[c]) * 1024 + h * 64 + gcc]);
      glds16(&Vsm[0][chunk * 512],
             &vtc[(size_t)(b * 1024 + h * 64 + vrow[c]) * 2048 + k0 + gcc]);
      glds16(&Ksm[1][chunk * 512],
             &kc[(size_t)(b * 2048 + k0 + 64 + prow[c]) * 1024 + h * 64 + gcc]);
      glds16(&Vsm[1][chunk * 512],
             &vtc[(size_t)(b * 1024 + h * 64 + vrow[c]) * 2048 + k0 + 64 + gcc]);
    }
    __syncthreads();

    SUBTILE(0, k0)
    if (k0 + 64 < nk) SUBTILE(1, k0 + 64)
  }
#undef SUBTILE

  // epilogue: osum rows == o rows (quad*4+r) — direct normalize, no shuffles
  #pragma unroll
  for (int i = 0; i < 4; i++)
    #pragma unroll
    for (int r = 0; r < 4; r++) {
      float inv = 1.f / osum[i][r];
      size_t row = (size_t)(b * 2048 + q0 + i * 16 + quad * 4 + r);
      #pragma unroll
      for (int jd = 0; jd < 4; jd++)
        ao[row * 1024 + h * 64 + jd * 16 + l15] = f2bf(o[i][jd][r] * inv);
    }
}

// ---------- kernel 4: output projection + bias ----------
__global__ __launch_bounds__(256, 3) void gemm_proj(const u16* __restrict__ A,
                                                    const u16* __restrict__ Bt,
                                                    const float* __restrict__ bias,
                                                    float* __restrict__ out) {
  __shared__ u16 Asm[128 * 64];
  __shared__ u16 Bsm[128 * 64];
  const int tid = threadIdx.x, lane = tid & 63, w = tid >> 6;
  const int quad = lane >> 4, l15 = lane & 15;
  const int m0 = blockIdx.y * 128, n0 = blockIdx.x * 128;
  const int wm = (w >> 1) * 64, wn = (w & 1) * 64;
  const int srow = lane >> 3;
  const int gcc = ((lane & 7) ^ srow) * 8;
  const int rx8 = (l15 & 7);
  f32x4 acc[4][4];
  #pragma unroll
  for (int i = 0; i < 4; i++)
    #pragma unroll
    for (int j = 0; j < 4; j++)
      #pragma unroll
      for (int r = 0; r < 4; r++) acc[i][j][r] = 0.f;

  for (int kt = 0; kt < 1024; kt += 64) {
    __syncthreads();
    #pragma unroll
    for (int c = 0; c < 4; ++c) {
      int chunk = w * 4 + c;
      int row = chunk * 8 + srow;
      glds16(&Asm[chunk * 512], &A[(size_t)(m0 + row) * 1024 + kt + gcc]);
      glds16(&Bsm[chunk * 512], &Bt[(size_t)(n0 + row) * 1024 + kt + gcc]);
    }
    __syncthreads();
    #pragma unroll
    for (int ks = 0; ks < 2; ++ks) {
      int pc = ((ks * 4 + quad) ^ rx8) * 8;
      short8 av[4], bv[4];
      #pragma unroll
      for (int i = 0; i < 4; i++)
        av[i] = *(const short8*)&Asm[(wm + i * 16 + l15) * 64 + pc];
      #pragma unroll
      for (int j = 0; j < 4; j++)
        bv[j] = *(const short8*)&Bsm[(wn + j * 16 + l15) * 64 + pc];
      #pragma unroll
      for (int i = 0; i < 4; i++)
        #pragma unroll
        for (int j = 0; j < 4; j++)
          acc[i][j] = MFMA(av[i], bv[j], acc[i][j]);
    }
  }

  #pragma unroll
  for (int j = 0; j < 4; j++) {
    int col = n0 + wn + j * 16 + l15;
    float bj = bias[col];
    #pragma unroll
    for (int i = 0; i < 4; i++) {
      #pragma unroll
      for (int r = 0; r < 4; r++) {
        int row = m0 + wm + i * 16 + quad * 4 + r;
        out[(size_t)row * 1024 + col] = acc[i][j][r] + bj;
      }
    }
  }
}

// ---------- launch ----------
extern "C" void kernel_launch(void* const* d_in, const int* in_sizes, int n_in,
                              void* d_out, int out_size, void* d_ws, size_t ws_size,
                              hipStream_t stream) {
  (void)in_sizes; (void)n_in; (void)out_size; (void)ws_size;
  const float* x     = (const float*)d_in[0];
  const int*   mask  = (const int*)d_in[1];
  const float* Wqkv  = (const float*)d_in[2];
  const float* Wproj = (const float*)d_in[3];
  const float* bproj = (const float*)d_in[4];
  float* out = (float*)d_out;
  char* ws = (char*)d_ws;

  size_t off = 0;
  u16* xb     = (u16*)(ws + off); off += 8192ull * 1024 * 2;   // x bf16; REUSED as aobuf
  u16* wqkvt  = (u16*)(ws + off); off += 3072ull * 1024 * 2;   // Wqkv^T bf16 [3072][1024]
  u16* wprojt = (u16*)(ws + off); off += 1024ull * 1024 * 2;   // Wproj^T bf16 [1024][1024]
  u16* qbuf   = (u16*)(ws + off); off += 8192ull * 1024 * 2;   // Q (pre-scaled) bf16
  u16* kcbuf  = (u16*)(ws + off); off += 4096ull * 2048 * 2;   // K compact [b][slot][1024]
  u16* vtcbuf = (u16*)(ws + off); off += 4096ull * 2048 * 2;   // V^T compact [b][d][slot]
  int* s2t    = (int*)(ws + off); off += 8192ull * 4;          // slot -> global token
  int* nkbuf  = (int*)(ws + off); off += 4 * 4;                // per-batch nk
  u16* aobuf  = xb;   // xb's last read is gemm_fused; attn writes ao after -> safe alias

  prep<<<9220, 256, 0, stream>>>(x, mask, Wqkv, Wproj, xb, wqkvt, wprojt, s2t, nkbuf);
  gemm_fused<<<1536, 256, 0, stream>>>(xb, wqkvt, s2t, nkbuf, qbuf, kcbuf, vtcbuf);
  attn_kernel<<<dim3(16, 4, 8), 256, 0, stream>>>(qbuf, kcbuf, vtcbuf, nkbuf, aobuf);
  gemm_proj<<<dim3(8, 64), 256, 0, stream>>>(aobuf, wprojt, bproj, out);
}

// Round 11
// 207.474 us; speedup vs baseline: 1.1569x; 1.0503x over previous
//
#include <hip/hip_runtime.h>

typedef unsigned short u16;
typedef unsigned int u32;
typedef unsigned long long u64;
typedef __attribute__((ext_vector_type(8))) short short8;
typedef __attribute__((ext_vector_type(4))) float f32x4;

#define QSCALE 0.18033688f   /* 0.125 * log2(e), folded into Q at projection */

// ---------- helpers ----------
__device__ __forceinline__ u16 f2bf(float f) {
  u32 u = __builtin_bit_cast(u32, f);
  u += 0x7fffu + ((u >> 16) & 1u);   // RNE
  return (u16)(u >> 16);
}

__device__ __forceinline__ float fexp2(float x) {
#if __has_builtin(__builtin_amdgcn_exp2f)
  return __builtin_amdgcn_exp2f(x);   // v_exp_f32
#else
  return exp2f(x);
#endif
}

// async global->LDS, 16B per lane. LDS dest is wave-uniform base + lane*16.
__device__ __forceinline__ void glds16(u16* lds, const u16* g) {
  __builtin_amdgcn_global_load_lds(
      (const __attribute__((address_space(1))) u32*)g,
      (__attribute__((address_space(3))) u32*)lds, 16, 0, 0);
}

#define MFMA(a, b, c) __builtin_amdgcn_mfma_f32_16x16x32_bf16((a), (b), (c), 0, 0, 0)

// LDS tile layout (XOR-swizzled), tile = [64 rows][64 u16 cols] = 8 KiB:
//   physical 16B-chunk slot p of row r holds logical col-chunk (p ^ (r&7)).
// b128 reads hit 8 distinct 16B regions per half-wave (4-way = b128 minimum).
//
// XCD swizzle (R10): blocks sharing the LARGE operand strip are spaced 64 apart
// in dispatch order (64 % 8 == 0 -> same XCD L2). Per-XCD working set: 8 strips
// x 256KB + 2MB weights ~ 4MB = L2 size. (R7 verified bid%8->XCD on this HW.)

// ---------- kernel 1: fused prep (x cvt | W transposes | mask scan) ----------
__global__ __launch_bounds__(256) void prep(const float* __restrict__ x,
                                            const int* __restrict__ mask,
                                            const float* __restrict__ Wqkv,
                                            const float* __restrict__ Wproj,
                                            u16* __restrict__ xb,
                                            u16* __restrict__ wqkvt,
                                            u16* __restrict__ wprojt,
                                            int* __restrict__ s2t,
                                            int* __restrict__ nkbuf) {
  __shared__ float tile[64][65];
  __shared__ int wtot[4];
  __shared__ int wbase[5];
  const int bid = blockIdx.x, t = threadIdx.x;

  if (bid < 8192) {                    // ---- role: x fp32 -> bf16 ----
    int i = bid * 256 + t;
    float4 v = ((const float4*)x)[i];
    union { u16 s[4]; u64 ll; } u;
    u.s[0] = f2bf(v.x); u.s[1] = f2bf(v.y); u.s[2] = f2bf(v.z); u.s[3] = f2bf(v.w);
    ((u64*)xb)[i] = u.ll;
    return;
  }
  if (bid < 9216) {                    // ---- role: W transpose+cvt ----
    const float* Wm; u16* Wt; int Cc, bj, bi;
    if (bid < 8960) { int tt = bid - 8192; Wm = Wqkv;  Wt = wqkvt;  Cc = 3072; bj = tt % 48; bi = tt / 48; }
    else            { int tt = bid - 8960; Wm = Wproj; Wt = wprojt; Cc = 1024; bj = tt & 15; bi = tt >> 4; }
    const int r = t >> 4, c4 = (t & 15) << 2;
    for (int rr = r; rr < 64; rr += 16) {
      float4 v = *(const float4*)&Wm[(size_t)(bi * 64 + rr) * Cc + bj * 64 + c4];
      tile[rr][c4] = v.x; tile[rr][c4 + 1] = v.y; tile[rr][c4 + 2] = v.z; tile[rr][c4 + 3] = v.w;
    }
    __syncthreads();
    for (int rr = r; rr < 64; rr += 16) {
      union { u16 s[4]; u64 ll; } u;
      u.s[0] = f2bf(tile[c4][rr]);
      u.s[1] = f2bf(tile[c4 + 1][rr]);
      u.s[2] = f2bf(tile[c4 + 2][rr]);
      u.s[3] = f2bf(tile[c4 + 3][rr]);
      *(u64*)&Wt[(size_t)(bj * 64 + rr) * 1024 + bi * 64 + c4] = u.ll;
    }
    return;
  }
  // ---- role: per-batch stable partition of key tokens ----
  const int b = bid - 9216;
  const int lane = t & 63, w = t >> 6;
  int m8[8], c = 0;
  #pragma unroll
  for (int j = 0; j < 8; j++) {
    m8[j] = (mask[b * 2048 + t * 8 + j] == 1);
    c += m8[j];
  }
  int incl = c;
  #pragma unroll
  for (int off = 1; off < 64; off <<= 1) {
    int v = __shfl_up(incl, off);
    if (lane >= off) incl += v;
  }
  if (lane == 63) wtot[w] = incl;
  __syncthreads();
  if (t == 0) {
    int s = 0;
    for (int i = 0; i < 4; i++) { wbase[i] = s; s += wtot[i]; }
    wbase[4] = s;
  }
  __syncthreads();
  const int nk = wbase[4];
  int urun = wbase[w] + incl - c;
  #pragma unroll
  for (int j = 0; j < 8; j++) {
    int tok = t * 8 + j;
    int slot = m8[j] ? urun : nk + (tok - urun);
    s2t[b * 2048 + slot] = b * 2048 + tok;
    urun += m8[j];
  }
  if (t == 0) nkbuf[b] = nk;
}

// ---------- kernel 2: fused Q/K/V GEMM, XCD-swizzled, compacted K/V ----------
// Q/K roles: m0=(sub&63)*128 (x-strip), n0=(sub>>6)*128 — same-strip blocks are
// 64 apart -> same XCD. V role mirrored: n0=(sub&63)*128 (gathered-x strip).
// Q-role epilogue pre-multiplies by QSCALE so attention's exp is bare exp2(s).
__global__ __launch_bounds__(256, 4) void gemm_fused(const u16* __restrict__ xb,
                                                     const u16* __restrict__ wqkvt,
                                                     const int* __restrict__ s2t,
                                                     const int* __restrict__ nkbuf,
                                                     u16* __restrict__ qbuf,
                                                     u16* __restrict__ kc,
                                                     u16* __restrict__ vtc) {
  __shared__ u16 Asm[128 * 64];
  __shared__ u16 Bsm[128 * 64];
  const int bid = blockIdx.x;
  const int role = bid >> 9;            // 0=Q 1=K 2=V
  const int sub = bid & 511;
  const int tid = threadIdx.x, lane = tid & 63, w = tid >> 6;
  const int quad = lane >> 4, l15 = lane & 15;
  const int wm = (w >> 1) * 64, wn = (w & 1) * 64;
  const int srow = lane >> 3;
  const int gcc = ((lane & 7) ^ srow) * 8;
  const int rx8 = (l15 & 7);

  int m0, n0;
  const u16 *Asrc, *Bsrc;
  if (role == 2) { m0 = (sub >> 6) * 128; n0 = (sub & 63) * 128; }
  else           { m0 = (sub & 63) * 128; n0 = (sub >> 6) * 128; }
  if (role == 1 && (m0 & 2047) >= nkbuf[m0 >> 11]) return;
  if (role == 2 && (n0 & 2047) >= nkbuf[n0 >> 11]) return;

  // per-lane source row ids for the 4 staged chunks
  int arow[4], brow[4];
  #pragma unroll
  for (int c = 0; c < 4; ++c) {
    int rit = (w * 4 + c) * 8 + srow;   // row within the 128-tile
    if (role == 0)      { arow[c] = m0 + rit;            brow[c] = n0 + rit; }
    else if (role == 1) { arow[c] = s2t[m0 + rit];       brow[c] = 1024 + n0 + rit; }
    else                { arow[c] = 2048 + m0 + rit;     brow[c] = s2t[n0 + rit]; }
  }
  Asrc = (role == 2) ? wqkvt : xb;
  Bsrc = (role == 2) ? xb : wqkvt;

  f32x4 acc[4][4];
  #pragma unroll
  for (int i = 0; i < 4; i++)
    #pragma unroll
    for (int j = 0; j < 4; j++)
      #pragma unroll
      for (int r = 0; r < 4; r++) acc[i][j][r] = 0.f;

  for (int kt = 0; kt < 1024; kt += 64) {
    __syncthreads();
    #pragma unroll
    for (int c = 0; c < 4; ++c) {
      int chunk = w * 4 + c;
      glds16(&Asm[chunk * 512], &Asrc[(size_t)arow[c] * 1024 + kt + gcc]);
      glds16(&Bsm[chunk * 512], &Bsrc[(size_t)brow[c] * 1024 + kt + gcc]);
    }
    __syncthreads();
    #pragma unroll
    for (int ks = 0; ks < 2; ++ks) {
      int pc = ((ks * 4 + quad) ^ rx8) * 8;
      short8 av[4], bv[4];
      #pragma unroll
      for (int i = 0; i < 4; i++)
        av[i] = *(const short8*)&Asm[(wm + i * 16 + l15) * 64 + pc];
      #pragma unroll
      for (int j = 0; j < 4; j++)
        bv[j] = *(const short8*)&Bsm[(wn + j * 16 + l15) * 64 + pc];
      #pragma unroll
      for (int i = 0; i < 4; i++)
        #pragma unroll
        for (int j = 0; j < 4; j++)
          acc[i][j] = MFMA(av[i], bv[j], acc[i][j]);
    }
  }

  if (role == 2) {
    #pragma unroll
    for (int j = 0; j < 4; j++) {
      int col = n0 + wn + j * 16 + l15;           // global slot 0..8191
      int bb = col >> 11, sl = col & 2047;
      #pragma unroll
      for (int i = 0; i < 4; i++)
        #pragma unroll
        for (int r = 0; r < 4; r++) {
          int row = m0 + wm + i * 16 + quad * 4 + r;   // d in 0..1023
          vtc[(size_t)(bb * 1024 + row) * 2048 + sl] = f2bf(acc[i][j][r]);
        }
    }
  } else {
    u16* dst = (role == 0) ? qbuf : kc;
    const float sc = (role == 0) ? QSCALE : 1.f;
    #pragma unroll
    for (int i = 0; i < 4; i++)
      #pragma unroll
      for (int j = 0; j < 4; j++) {
        int col = n0 + wn + j * 16 + l15;
        #pragma unroll
        for (int r = 0; r < 4; r++) {
          int row = m0 + wm + i * 16 + quad * 4 + r;
          dst[(size_t)row * 1024 + col] = f2bf(acc[i][j][r] * sc);
        }
      }
  }
}

// ---------- kernel 3: flash attention, register P, BK=128, MFMA row-sums ----------
__global__ __launch_bounds__(256, 2) void attn_kernel(const u16* __restrict__ q,
                                                      const u16* __restrict__ kc,
                                                      const u16* __restrict__ vtc,
                                                      const int* __restrict__ nkbuf,
                                                      u16* __restrict__ ao) {
  __shared__ u16 Ksm[2][64 * 64];       // π-permuted key rows, swizzled cols (d)
  __shared__ u16 Vsm[2][64 * 64];       // [d][k_local] linear keys, swizzled
  const int h = blockIdx.x, b = blockIdx.y, qt = blockIdx.z;
  const int tid = threadIdx.x, lane = tid & 63, w = tid >> 6;
  const int quad = lane >> 4, l15 = lane & 15;
  const int q0 = qt * 256 + w * 64;     // wave's q base within batch
  const int srow = lane >> 3;
  const int gcc = ((lane & 7) ^ srow) * 8;
  const int rx8 = (l15 & 7);
  const int nk = nkbuf[b];
  const int nt2 = (nk + 127) >> 7;
  const int quad8 = quad * 8;

  // staging rows + π for K source
  int vrow[2], prow[2];
  #pragma unroll
  for (int c = 0; c < 2; ++c) {
    int row = (w * 2 + c) * 8 + srow;
    vrow[c] = row;
    prow[c] = ((row >> 4) & 1) * 32 + ((row >> 2) & 3) * 8 + ((row >> 5) & 1) * 4 + (row & 3);
  }

  // ones B-fragment (bf16 1.0 splat) for MFMA row-sums
  short8 ones;
  #pragma unroll
  for (int z = 0; z < 8; z++) ones[z] = (short)0x3F80;

  // Q fragments (B-operand): n=q=l15(+16i), k=d=quad*8+j (+32ks)
  short8 qf[4][2];
  #pragma unroll
  for (int i = 0; i < 4; i++)
    #pragma unroll
    for (int ks = 0; ks < 2; ks++)
      qf[i][ks] = *(const short8*)&q[(size_t)(b * 2048 + q0 + i * 16 + l15) * 1024 +
                                     h * 64 + ks * 32 + quad * 8];

  f32x4 o[4][4], osum[4];
  #pragma unroll
  for (int i = 0; i < 4; i++) {
    #pragma unroll
    for (int r = 0; r < 4; r++) osum[i][r] = 0.f;
    #pragma unroll
    for (int jd = 0; jd < 4; jd++)
      #pragma unroll
      for (int r = 0; r < 4; r++) o[i][jd][r] = 0.f;
  }

#define SUBTILE(st_, kbase_)                                                           \
  {                                                                                    \
    f32x4 s[4][4];                                                                     \
    _Pragma("unroll") for (int j = 0; j < 4; j++)                                      \
      _Pragma("unroll") for (int i = 0; i < 4; i++)                                    \
        _Pragma("unroll") for (int r = 0; r < 4; r++) s[j][i][r] = 0.f;                \
    _Pragma("unroll") for (int ks = 0; ks < 2; ks++) {                                 \
      int pc = ((ks * 4 + quad) ^ rx8) * 8;                                            \
      short8 kf[4];                                                                    \
      _Pragma("unroll") for (int j = 0; j < 4; j++)                                    \
        kf[j] = *(const short8*)&Ksm[st_][(j * 16 + l15) * 64 + pc];                   \
      _Pragma("unroll") for (int j = 0; j < 4; j++)                                    \
        _Pragma("unroll") for (int i = 0; i < 4; i++)                                  \
          s[j][i] = MFMA(kf[j], qf[i][ks], s[j][i]);                                   \
    }                                                                                  \
    const bool tail = ((kbase_) + 64 > nk);                                            \
    short8 pf[4][2];                                                                   \
    _Pragma("unroll") for (int i = 0; i < 4; i++) {                                    \
      float p[4][4];                                                                   \
      if (!tail) {                                                                     \
        _Pragma("unroll") for (int j = 0; j < 4; j++)                                  \
          _Pragma("unroll") for (int r = 0; r < 4; r++)                                \
            p[j][r] = fexp2(s[j][i][r]);                                               \
      } else {                                                                         \
        _Pragma("unroll") for (int j = 0; j < 4; j++)                                  \
          _Pragma("unroll") for (int r = 0; r < 4; r++) {                              \
            int slot = (kbase_) + (j & 1) * 32 + quad8 + (j >> 1) * 4 + r;             \
            float e = fexp2(s[j][i][r]);                                               \
            p[j][r] = (slot < nk) ? e : 0.f;                                           \
          }                                                                            \
      }                                                                                \
      _Pragma("unroll") for (int ks = 0; ks < 2; ks++) {                               \
        union { u32 u[4]; short8 v; } pk;                                              \
        u32 a0 = __builtin_bit_cast(u32, p[ks][0]) + 0x8000u;                          \
        u32 a1 = __builtin_bit_cast(u32, p[ks][1]) + 0x8000u;                          \
        u32 a2 = __builtin_bit_cast(u32, p[ks][2]) + 0x8000u;                          \
        u32 a3 = __builtin_bit_cast(u32, p[ks][3]) + 0x8000u;                          \
        u32 b0 = __builtin_bit_cast(u32, p[ks + 2][0]) + 0x8000u;                      \
        u32 b1 = __builtin_bit_cast(u32, p[ks + 2][1]) + 0x8000u;                      \
        u32 b2 = __builtin_bit_cast(u32, p[ks + 2][2]) + 0x8000u;                      \
        u32 b3 = __builtin_bit_cast(u32, p[ks + 2][3]) + 0x8000u;                      \
        pk.u[0] = __builtin_amdgcn_perm(a1, a0, 0x07060302u);                          \
        pk.u[1] = __builtin_amdgcn_perm(a3, a2, 0x07060302u);                          \
        pk.u[2] = __builtin_amdgcn_perm(b1, b0, 0x07060302u);                          \
        pk.u[3] = __builtin_amdgcn_perm(b3, b2, 0x07060302u);                          \
        pf[i][ks] = pk.v;                                                              \
      }                                                                                \
    }                                                                                  \
    _Pragma("unroll") for (int ks = 0; ks < 2; ks++) {                                 \
      int pcv = ((ks * 4 + quad) ^ rx8) * 8;                                           \
      short8 vf[4];                                                                    \
      _Pragma("unroll") for (int jd = 0; jd < 4; jd++)                                 \
        vf[jd] = *(const short8*)&Vsm[st_][(jd * 16 + l15) * 64 + pcv];                \
      _Pragma("unroll") for (int i = 0; i < 4; i++) {                                  \
        osum[i] = MFMA(pf[i][ks], ones, osum[i]);                                      \
        _Pragma("unroll") for (int jd = 0; jd < 4; jd++)                               \
          o[i][jd] = MFMA(pf[i][ks], vf[jd], o[i][jd]);                                \
      }                                                                                \
    }                                                                                  \
  }

  for (int t = 0; t < nt2; ++t) {
    const int k0 = t * 128;
    __syncthreads();
    #pragma unroll
    for (int c = 0; c < 2; ++c) {
      int chunk = w * 2 + c;
      glds16(&Ksm[0][chunk * 512],
             &kc[(size_t)(b * 2048 + k0 + prow[c]) * 1024 + h * 64 + gcc]);
      glds16(&Vsm[0][chunk * 512],
             &vtc[(size_t)(b * 1024 + h * 64 + vrow[c]) * 2048 + k0 + gcc]);
      glds16(&Ksm[1][chunk * 512],
             &kc[(size_t)(b * 2048 + k0 + 64 + prow[c]) * 1024 + h * 64 + gcc]);
      glds16(&Vsm[1][chunk * 512],
             &vtc[(size_t)(b * 1024 + h * 64 + vrow[c]) * 2048 + k0 + 64 + gcc]);
    }
    __syncthreads();

    SUBTILE(0, k0)
    if (k0 + 64 < nk) SUBTILE(1, k0 + 64)
  }
#undef SUBTILE

  // epilogue: osum rows == o rows (quad*4+r) — direct normalize, no shuffles
  #pragma unroll
  for (int i = 0; i < 4; i++)
    #pragma unroll
    for (int r = 0; r < 4; r++) {
      float inv = 1.f / osum[i][r];
      size_t row = (size_t)(b * 2048 + q0 + i * 16 + quad * 4 + r);
      #pragma unroll
      for (int jd = 0; jd < 4; jd++)
        ao[row * 1024 + h * 64 + jd * 16 + l15] = f2bf(o[i][jd][r] * inv);
    }
}

// ---------- kernel 4: output projection + bias (XCD-swizzled flat grid) ----------
// 512 blocks: m0=(bid&63)*128 (aobuf strip, 16MB operand), n0=(bid>>6)*128.
__global__ __launch_bounds__(256, 3) void gemm_proj(const u16* __restrict__ A,
                                                    const u16* __restrict__ Bt,
                                                    const float* __restrict__ bias,
                                                    float* __restrict__ out) {
  __shared__ u16 Asm[128 * 64];
  __shared__ u16 Bsm[128 * 64];
  const int tid = threadIdx.x, lane = tid & 63, w = tid >> 6;
  const int quad = lane >> 4, l15 = lane & 15;
  const int m0 = (blockIdx.x & 63) * 128, n0 = (blockIdx.x >> 6) * 128;
  const int wm = (w >> 1) * 64, wn = (w & 1) * 64;
  const int srow = lane >> 3;
  const int gcc = ((lane & 7) ^ srow) * 8;
  const int rx8 = (l15 & 7);
  f32x4 acc[4][4];
  #pragma unroll
  for (int i = 0; i < 4; i++)
    #pragma unroll
    for (int j = 0; j < 4; j++)
      #pragma unroll
      for (int r = 0; r < 4; r++) acc[i][j][r] = 0.f;

  for (int kt = 0; kt < 1024; kt += 64) {
    __syncthreads();
    #pragma unroll
    for (int c = 0; c < 4; ++c) {
      int chunk = w * 4 + c;
      int row = chunk * 8 + srow;
      glds16(&Asm[chunk * 512], &A[(size_t)(m0 + row) * 1024 + kt + gcc]);
      glds16(&Bsm[chunk * 512], &Bt[(size_t)(n0 + row) * 1024 + kt + gcc]);
    }
    __syncthreads();
    #pragma unroll
    for (int ks = 0; ks < 2; ++ks) {
      int pc = ((ks * 4 + quad) ^ rx8) * 8;
      short8 av[4], bv[4];
      #pragma unroll
      for (int i = 0; i < 4; i++)
        av[i] = *(const short8*)&Asm[(wm + i * 16 + l15) * 64 + pc];
      #pragma unroll
      for (int j = 0; j < 4; j++)
        bv[j] = *(const short8*)&Bsm[(wn + j * 16 + l15) * 64 + pc];
      #pragma unroll
      for (int i = 0; i < 4; i++)
        #pragma unroll
        for (int j = 0; j < 4; j++)
          acc[i][j] = MFMA(av[i], bv[j], acc[i][j]);
    }
  }

  #pragma unroll
  for (int j = 0; j < 4; j++) {
    int col = n0 + wn + j * 16 + l15;
    float bj = bias[col];
    #pragma unroll
    for (int i = 0; i < 4; i++) {
      #pragma unroll
      for (int r = 0; r < 4; r++) {
        int row = m0 + wm + i * 16 + quad * 4 + r;
        out[(size_t)row * 1024 + col] = acc[i][j][r] + bj;
      }
    }
  }
}

// ---------- launch ----------
extern "C" void kernel_launch(void* const* d_in, const int* in_sizes, int n_in,
                              void* d_out, int out_size, void* d_ws, size_t ws_size,
                              hipStream_t stream) {
  (void)in_sizes; (void)n_in; (void)out_size; (void)ws_size;
  const float* x     = (const float*)d_in[0];
  const int*   mask  = (const int*)d_in[1];
  const float* Wqkv  = (const float*)d_in[2];
  const float* Wproj = (const float*)d_in[3];
  const float* bproj = (const float*)d_in[4];
  float* out = (float*)d_out;
  char* ws = (char*)d_ws;

  size_t off = 0;
  u16* xb     = (u16*)(ws + off); off += 8192ull * 1024 * 2;   // x bf16; REUSED as aobuf
  u16* wqkvt  = (u16*)(ws + off); off += 3072ull * 1024 * 2;   // Wqkv^T bf16 [3072][1024]
  u16* wprojt = (u16*)(ws + off); off += 1024ull * 1024 * 2;   // Wproj^T bf16 [1024][1024]
  u16* qbuf   = (u16*)(ws + off); off += 8192ull * 1024 * 2;   // Q (pre-scaled) bf16
  u16* kcbuf  = (u16*)(ws + off); off += 4096ull * 2048 * 2;   // K compact [b][slot][1024]
  u16* vtcbuf = (u16*)(ws + off); off += 4096ull * 2048 * 2;   // V^T compact [b][d][slot]
  int* s2t    = (int*)(ws + off); off += 8192ull * 4;          // slot -> global token
  int* nkbuf  = (int*)(ws + off); off += 4 * 4;                // per-batch nk
  u16* aobuf  = xb;   // xb's last read is gemm_fused; attn writes ao after -> safe alias

  prep<<<9220, 256, 0, stream>>>(x, mask, Wqkv, Wproj, xb, wqkvt, wprojt, s2t, nkbuf);
  gemm_fused<<<1536, 256, 0, stream>>>(xb, wqkvt, s2t, nkbuf, qbuf, kcbuf, vtcbuf);
  attn_kernel<<<dim3(16, 4, 8), 256, 0, stream>>>(qbuf, kcbuf, vtcbuf, nkbuf, aobuf);
  gemm_proj<<<512, 256, 0, stream>>>(aobuf, wprojt, bproj, out);
}